// Round 11
// baseline (136.578 us; speedup 1.0000x reference)
//
#include <hip/hip_runtime.h>

// GATConv fused pipeline, MI355X.
// R11: k_aggr -> MFMA aggregation. Wave owns 16 dsts: OUT[16x64]=A[16xK]·H[Kx64]
//   per K=32 step: A (alpha, bf16) built in LDS; 32 h-rows gathered to LDS
//   (XOR chunk-swizzle vs 4-way bank conflict on column reads); 4 MFMA + 1
//   ones-MFMA (per-dst weight sums, free, same C layout). No scalar epilogue
//   reduction. Self-loops inlined as edges by fsort (stride SCAP+256).
// R10 counters: k_aggr 50us — per-dst fixed cost (24-shuffle epilogue +
//   wave_sum) ~= edge-loop cost; scalar path at structural floor.
// A/B/C fragment layouts identical to R8's verified k_gemm usage.
// word = dst_low:8 | src:17 (n<=131072).

#define NEG_SLOPE 0.2f
#define NBC_MAX 512
#define SCAP 6144
#define EWPS (SCAP + 256)   // ewp per-bucket stride (self slots inlined)

typedef __attribute__((ext_vector_type(8))) short bf16x8;
typedef __attribute__((ext_vector_type(4))) float f32x4;

__device__ __forceinline__ float leaky(float v) {
    return v > 0.f ? v : NEG_SLOPE * v;
}
__device__ __forceinline__ float wave_sum(float v) {
    for (int o = 32; o; o >>= 1) v += __shfl_xor(v, o);
    return v;
}
__device__ __forceinline__ unsigned short f2bf(float f) {
    unsigned b = __float_as_uint(f);
    return (unsigned short)((b + 0x7FFFu + ((b >> 16) & 1u)) >> 16);
}
__device__ __forceinline__ float bf2f(unsigned short u) {
    return __uint_as_float(((unsigned)u) << 16);
}

// exclusive scan of sd[0..len) in place; sd must have len+1 slots.
__device__ __forceinline__ void lds_excl_scan(int* sd, int len) {
    __syncthreads();
    if (threadIdx.x < 64) {
        int lane = threadIdx.x;
        int carry = 0;
        for (int c0 = 0; c0 < len; c0 += 64) {
            int idx = c0 + lane;
            int v = (idx < len) ? sd[idx] : 0;
            int s = v;
            for (int off = 1; off < 64; off <<= 1) {
                int t = __shfl_up(s, off);
                if (lane >= off) s += t;
            }
            if (idx < len) sd[idx] = carry + s - v;
            carry += __shfl(s, 63);
        }
        if (lane == 0) sd[len] = carry;
    }
    __syncthreads();
}

// ------------------------------------------------- h(bf16) = x@W via MFMA
__global__ __launch_bounds__(256) void k_gemm(
    const float* __restrict__ x, const float* __restrict__ Wg,
    const float* __restrict__ att_s, const float* __restrict__ att_d,
    unsigned short* __restrict__ h2, float* __restrict__ a_src,
    float* __restrict__ a_dst, int n) {
    __shared__ unsigned short Wh[64 * 136];   // 17 KB
    __shared__ unsigned short Wl2[64 * 136];  // 17 KB
    {
        const float4* wg4 = (const float4*)Wg;  // [k=128][col=64] row-major
#pragma unroll
        for (int i = 0; i < 8; ++i) {
            int f = threadIdx.x + i * 256;  // [0, 2048)
            float4 w = wg4[f];
            int k = f >> 4;
            int c0 = (f & 15) << 2;
            float vv[4] = {w.x, w.y, w.z, w.w};
#pragma unroll
            for (int j = 0; j < 4; ++j) {
                unsigned short hi = f2bf(vv[j]);
                Wh[(c0 + j) * 136 + k] = hi;
                Wl2[(c0 + j) * 136 + k] = f2bf(vv[j] - bf2f(hi));
            }
        }
    }
    __syncthreads();

    const int lane = threadIdx.x & 63;
    const int wave = threadIdx.x >> 6;
    const int rb = blockIdx.x * 64 + wave * 16;
    const int arow = rb + (lane & 15);
    const int kb = (lane >> 4) << 3;
    const int col = lane & 15;

    f32x4 acc[4];
#pragma unroll
    for (int ct = 0; ct < 4; ++ct) acc[ct] = (f32x4){0.f, 0.f, 0.f, 0.f};

#pragma unroll
    for (int ks = 0; ks < 4; ++ks) {
        const int k0 = ks * 32 + kb;
        float av[8];
        if (arow < n) {
            float4 a0 = *(const float4*)(x + (size_t)arow * 128 + k0);
            float4 a1 = *(const float4*)(x + (size_t)arow * 128 + k0 + 4);
            av[0] = a0.x; av[1] = a0.y; av[2] = a0.z; av[3] = a0.w;
            av[4] = a1.x; av[5] = a1.y; av[6] = a1.z; av[7] = a1.w;
        } else {
#pragma unroll
            for (int j = 0; j < 8; ++j) av[j] = 0.f;
        }
        bf16x8 ah, al;
#pragma unroll
        for (int j = 0; j < 8; ++j) {
            unsigned short hi = f2bf(av[j]);
            ah[j] = (short)hi;
            al[j] = (short)f2bf(av[j] - bf2f(hi));
        }
#pragma unroll
        for (int ct = 0; ct < 4; ++ct) {
            const bf16x8 bh = *(const bf16x8*)(&Wh[(ct * 16 + col) * 136 + k0]);
            const bf16x8 bl = *(const bf16x8*)(&Wl2[(ct * 16 + col) * 136 + k0]);
            acc[ct] = __builtin_amdgcn_mfma_f32_16x16x32_bf16(ah, bh, acc[ct], 0, 0, 0);
            acc[ct] = __builtin_amdgcn_mfma_f32_16x16x32_bf16(al, bh, acc[ct], 0, 0, 0);
            acc[ct] = __builtin_amdgcn_mfma_f32_16x16x32_bf16(ah, bl, acc[ct], 0, 0, 0);
        }
    }

    float as_f[4], ad_f[4];
#pragma unroll
    for (int ct = 0; ct < 4; ++ct) {
        as_f[ct] = att_s[ct * 16 + col];
        ad_f[ct] = att_d[ct * 16 + col];
    }
#pragma unroll
    for (int reg = 0; reg < 4; ++reg) {
        const int row = rb + ((lane >> 4) << 2) + reg;
        float s = 0.f, t = 0.f;
#pragma unroll
        for (int ct = 0; ct < 4; ++ct) {
            float v = acc[ct][reg];
            s = fmaf(v, as_f[ct], s);
            t = fmaf(v, ad_f[ct], t);
            if (row < n) h2[(size_t)row * 64 + ct * 16 + col] = f2bf(v);
        }
#pragma unroll
        for (int o = 1; o < 16; o <<= 1) {
            s += __shfl_xor(s, o);
            t += __shfl_xor(t, o);
        }
        if (col == 0 && row < n) { a_src[row] = s; a_dst[row] = t; }
    }
}

// ------------------------------------------------- coarse scatter (LDS reorder)
__global__ __launch_bounds__(256) void k_cscatter(
    const int* __restrict__ srcv, const int* __restrict__ dstv,
    int* __restrict__ gcursor, int* __restrict__ words, int e, int nbc) {
    __shared__ int sc[NBC_MAX + 1];
    __shared__ int offs[NBC_MAX];
    __shared__ int gbase[NBC_MAX];
    __shared__ int lim[NBC_MAX];
    __shared__ int2 staged[4096];
    for (int t = threadIdx.x; t < nbc; t += 256) { sc[t] = 0; offs[t] = 0; }
    __syncthreads();
    const int base = blockIdx.x * 4096;
    int s_[16], d_[16];
#pragma unroll
    for (int k = 0; k < 16; ++k) {
        int i = base + k * 256 + threadIdx.x;
        if (i < e) {
            s_[k] = srcv[i];
            d_[k] = dstv[i];
            atomicAdd(&sc[d_[k] >> 8], 1);
        } else {
            d_[k] = -1;
        }
    }
    lds_excl_scan(sc, nbc);
    for (int t = threadIdx.x; t < nbc; t += 256) {
        int c = sc[t + 1] - sc[t];
        if (c) {
            int r0 = atomicAdd(&gcursor[t], c);
            gbase[t] = t * SCAP + r0;
            lim[t] = max(0, SCAP - r0);
        }
    }
    __syncthreads();
#pragma unroll
    for (int k = 0; k < 16; ++k) {
        if (d_[k] >= 0) {
            int b = d_[k] >> 8;
            int r = atomicAdd(&offs[b], 1);
            staged[sc[b] + r] = make_int2(s_[k], d_[k]);
        }
    }
    __syncthreads();
    const int tot = sc[nbc];
    for (int p = threadIdx.x; p < tot; p += 256) {
        int2 pr = staged[p];
        int b = pr.y >> 8;
        int off2 = p - sc[b];
        if (off2 < lim[b]) {
            int word = ((pr.y & 255) << 17) | pr.x;  // dst_low:8 | src:17
            words[gbase[b] + off2] = word;
        }
    }
}

// ------------------------------------------------- fine sort + edge exp
// sorts bucket by dst_low; writes ewp with SELF-LOOP INLINED at each segment
// start (stride EWPS); rowptrB[b*257+t] = b*EWPS + rp[t] + min(t,ndl).
__global__ __launch_bounds__(256) void k_fsort(
    const int* __restrict__ words, const int* __restrict__ gcursor,
    const float* __restrict__ a_src, const float* __restrict__ a_dst,
    int2* __restrict__ ewp, int* __restrict__ rowptrB, int n) {
    __shared__ int rp[257];
    __shared__ int offs[256];
    __shared__ int sorted_[SCAP];   // 24 KB
    __shared__ float adst_l[256];
    const int b = blockIdx.x;
    const int d0 = b << 8;
    const int ndl = min(256, n - d0);
    const int base = b * SCAP;
    const int base2 = b * EWPS;
    const int cnt = min(gcursor[b], SCAP);
    const int tid = threadIdx.x;
    rp[tid] = 0;
    offs[tid] = 0;
    if (tid == 0) rp[256] = 0;
    if (tid < ndl) adst_l[tid] = a_dst[d0 + tid];
    __syncthreads();
    // histogram (read 1)
    for (int p = tid; p < cnt; p += 256)
        atomicAdd(&rp[(words[base + p] >> 17) & 255], 1);
    lds_excl_scan(rp, 256);
    // reorder into LDS (read 2)
    for (int p = tid; p < cnt; p += 256) {
        int w = words[base + p];
        int dl = (w >> 17) & 255;
        int r = atomicAdd(&offs[dl], 1);
        sorted_[rp[dl] + r] = w;
    }
    __syncthreads();
    // self-loop slot at each segment start
    if (tid < ndl) {
        int d = d0 + tid;
        float ws = __expf(leaky(a_src[d] + adst_l[tid]));
        ewp[base2 + rp[tid] + tid] = make_int2(d, __float_as_int(ws));
    }
    // edges shifted by (dl+1)
    for (int p = tid; p < cnt; p += 256) {
        int w = sorted_[p];
        int dl = (w >> 17) & 255;
        float al = __expf(leaky(a_src[w & 0x1FFFF] + adst_l[dl]));
        ewp[base2 + p + dl + 1] = make_int2(w, __float_as_int(al));
    }
    for (int t = tid; t <= 256; t += 256)
        rowptrB[b * 257 + t] = base2 + rp[t] + min(t, ndl);
}

// ------------------------------------------------- MFMA aggregate
// wave owns 16 dsts (contiguous, within one bucket). Per K=32 step:
// A[16x32] alpha (bf16, LDS), H[32x64] gathered rows (LDS, chunk-XOR-swizzled),
// 4x mfma_16x16x32 + 1 ones-mfma (weight sums). C layout = [dst][feat].
__global__ __launch_bounds__(256) void k_aggr(
    const unsigned short* __restrict__ h2, const int* __restrict__ rowptrB,
    const int2* __restrict__ ewp, float* __restrict__ out, int n) {
    // per-wave LDS slices
    __shared__ unsigned short Hs[4][32 * 80];  // 160B rows, 16B chunk-swizzled
    __shared__ unsigned short As[4][16 * 40];  // 80B rows (16B-aligned frags)
    __shared__ short SD[4][768];               // slot -> local dst
    __shared__ int BND[4][17];                 // segment bounds
    const int lane = threadIdx.x & 63;
    const int wave = threadIdx.x >> 6;
    const int g = blockIdx.x * 4 + wave;
    const int d0 = g * 16;
    if (d0 >= n) return;
    const int b = d0 >> 8;
    const int dl0 = d0 & 255;

    if (lane < 17) BND[wave][lane] = rowptrB[b * 257 + dl0 + lane];
    const int s0 = BND[wave][0];
    const int K = min(BND[wave][16] - s0, 768);

    // slot -> local dst via 4-step binary search over bounds
    for (int s = lane; s < K; s += 64) {
        int lo = 0, hi = 16;
        int abs_s = s0 + s;
#pragma unroll
        for (int it = 0; it < 4; ++it) {
            int mid = (lo + hi) >> 1;
            if (BND[wave][mid] <= abs_s) lo = mid; else hi = mid;
        }
        SD[wave][s] = (short)lo;
    }

    f32x4 acc0 = {0,0,0,0}, acc1 = {0,0,0,0}, acc2 = {0,0,0,0},
          acc3 = {0,0,0,0}, accw = {0,0,0,0};
    bf16x8 ones;
#pragma unroll
    for (int j = 0; j < 8; ++j) ones[j] = (short)0x3F80;

    const int rowgrp = lane >> 4;   // 0..3
    const int col = lane & 15;
    const int nstep = (K + 31) >> 5;
    for (int st = 0; st < nstep; ++st) {
        const int kbase = st << 5;
        // zero A (16 rows x 32 cols used region)
        {
            int4 z = make_int4(0, 0, 0, 0);
            *(int4*)((char*)&As[wave][0] + (lane >> 2) * 80 + (lane & 3) * 16) = z;
        }
        // fill A: lane<32 handles slot kbase+lane
        if (lane < 32) {
            int s = kbase + lane;
            if (s < K) {
                int2 p = ewp[s0 + s];
                int dl = SD[wave][s];
                As[wave][dl * 40 + lane] = f2bf(__int_as_float(p.y));
            }
        }
        // stage H: 4 sub-iters x 8 rows; chunk-swizzle ^((k>>3)&3)
#pragma unroll
        for (int i = 0; i < 4; ++i) {
            int kk = kbase + i * 8 + (lane >> 3);
            if (kk < K) {
                int src = ewp[s0 + kk].x & 0x1FFFF;  // 8 lanes same addr
                int4 u = *(const int4*)(h2 + (size_t)src * 64 + (lane & 7) * 8);
                int kr = kk & 31;
                int chunk = (lane & 7) ^ ((kr >> 3) & 3);
                *(int4*)((char*)&Hs[wave][0] + kr * 160 + chunk * 16) = u;
            }
        }
        // A frag (R8-verified layout: row=lane&15, k=(lane>>4)*8+j)
        bf16x8 af = *(const bf16x8*)((char*)&As[wave][0] + col * 80 + rowgrp * 16);
        accw = __builtin_amdgcn_mfma_f32_16x16x32_bf16(af, ones, accw, 0, 0, 0);
        // B frags per feature tile: 8 column ushort reads (swizzled)
#pragma unroll
        for (int ct = 0; ct < 4; ++ct) {
            bf16x8 bf;
#pragma unroll
            for (int j = 0; j < 8; ++j) {
                int k = rowgrp * 8 + j;
                int c = ct * 16 + col;
                int chunk = (c >> 3) ^ ((k >> 3) & 3);
                bf[j] = *(const short*)((char*)&Hs[wave][0] + k * 160 +
                                        chunk * 16 + (c & 7) * 2);
            }
            switch (ct) {
                case 0: acc0 = __builtin_amdgcn_mfma_f32_16x16x32_bf16(af, bf, acc0, 0, 0, 0); break;
                case 1: acc1 = __builtin_amdgcn_mfma_f32_16x16x32_bf16(af, bf, acc1, 0, 0, 0); break;
                case 2: acc2 = __builtin_amdgcn_mfma_f32_16x16x32_bf16(af, bf, acc2, 0, 0, 0); break;
                case 3: acc3 = __builtin_amdgcn_mfma_f32_16x16x32_bf16(af, bf, acc3, 0, 0, 0); break;
            }
        }
    }
    // epilogue: C layout col=lane&15, dst=(lane>>4)*4+reg; divide by wsum
#pragma unroll
    for (int reg = 0; reg < 4; ++reg) {
        int dst = d0 + rowgrp * 4 + reg;
        if (dst < n) {
            float inv = 1.0f / (accw[reg] + 1e-16f);
            float* op = out + (size_t)dst * 64 + col;
            op[0]  = acc0[reg] * inv;
            op[16] = acc1[reg] * inv;
            op[32] = acc2[reg] * inv;
            op[48] = acc3[reg] * inv;
        }
    }
}

extern "C" void kernel_launch(void* const* d_in, const int* in_sizes, int n_in,
                              void* d_out, int out_size, void* d_ws, size_t ws_size,
                              hipStream_t stream) {
    const float* x = (const float*)d_in[0];
    const float* W = (const float*)d_in[1];
    const float* att_s = (const float*)d_in[2];
    const float* att_d = (const float*)d_in[3];
    const int* ei = (const int*)d_in[4];
    const int n = in_sizes[0] / 128;
    const int e = in_sizes[4] / 2;
    const int* srcv = ei;
    const int* dstv = ei + e;
    float* out = (float*)d_out;

    char* ws = (char*)d_ws;
    size_t off = 0;
    auto carve = [&](size_t bytes) -> void* {
        void* p = ws + off;
        off = (off + bytes + 63) & ~(size_t)63;
        return p;
    };
    const int nbc = (n + 255) >> 8;  // coarse buckets (<= NBC_MAX)
    unsigned short* h2 = (unsigned short*)carve((size_t)n * 64 * 2);
    float* a_src  = (float*)carve((size_t)n * 4);
    float* a_dst  = (float*)carve((size_t)n * 4);
    int* gcursor  = (int*)carve((size_t)NBC_MAX * 4);
    int* rowptrB  = (int*)carve((size_t)nbc * 257 * 4);
    int* words    = (int*)carve((size_t)nbc * SCAP * 4);
    int2* ewp     = (int2*)carve((size_t)nbc * EWPS * 8);
    (void)ws_size; (void)n_in; (void)out_size;

    const int neb = (e + 4095) / 4096;
    const int ngrp = (n + 15) / 16;

    hipMemsetAsync(gcursor, 0, (size_t)NBC_MAX * 4, stream);

    k_gemm<<<(n + 63) / 64, 256, 0, stream>>>(x, W, att_s, att_d, h2, a_src, a_dst, n);
    k_cscatter<<<neb, 256, 0, stream>>>(srcv, dstv, gcursor, words, e, nbc);
    k_fsort<<<nbc, 256, 0, stream>>>(words, gcursor, a_src, a_dst, ewp, rowptrB, n);
    k_aggr<<<(ngrp + 3) / 4, 256, 0, stream>>>(h2, rowptrB, ewp, out, n);
}

// Round 12
// 110.354 us; speedup vs baseline: 1.2376x; 1.2376x over previous
//
#include <hip/hip_runtime.h>

// GATConv fused pipeline, MI355X.
// R12: R11's MFMA aggregation REVERTED (4.3M LDS bank conflicts from scalar
//   ushort B-frag reads; MfmaUtil 2.5%, 66us vs R10's 50us). k_aggr/k_fsort
//   back to R10 forms (lane-owns-edge scalar aggregate, no-max softmax).
//   k_gemm slimmed to SINGLE-TERM bf16 MFMA (split-bf16 corrections dropped:
//   ~0.3% rel err on h, same order as bf16 h2 storage; halves LDS, cuts
//   cvt VALU 56->16 per kstep).
// word = dst_low:8 | src:17 (n<=131072). rowptrB[b*257+dl] = abs seg starts.

#define NEG_SLOPE 0.2f
#define NBC_MAX 512
#define SCAP 6144

typedef __attribute__((ext_vector_type(8))) short bf16x8;
typedef __attribute__((ext_vector_type(4))) float f32x4;

__device__ __forceinline__ float leaky(float v) {
    return v > 0.f ? v : NEG_SLOPE * v;
}
__device__ __forceinline__ float wave_sum(float v) {
    for (int o = 32; o; o >>= 1) v += __shfl_xor(v, o);
    return v;
}
__device__ __forceinline__ unsigned short f2bf(float f) {
    unsigned b = __float_as_uint(f);
    return (unsigned short)((b + 0x7FFFu + ((b >> 16) & 1u)) >> 16);
}
__device__ __forceinline__ float bf2f(unsigned short u) {
    return __uint_as_float(((unsigned)u) << 16);
}
// fma 8 bf16 features (packed in int4) into acc[8] with weight w
__device__ __forceinline__ void bf8_fma(float* acc, int4 u, float w) {
    acc[0] = fmaf(__uint_as_float((unsigned)u.x << 16), w, acc[0]);
    acc[1] = fmaf(__uint_as_float((unsigned)u.x & 0xFFFF0000u), w, acc[1]);
    acc[2] = fmaf(__uint_as_float((unsigned)u.y << 16), w, acc[2]);
    acc[3] = fmaf(__uint_as_float((unsigned)u.y & 0xFFFF0000u), w, acc[3]);
    acc[4] = fmaf(__uint_as_float((unsigned)u.z << 16), w, acc[4]);
    acc[5] = fmaf(__uint_as_float((unsigned)u.z & 0xFFFF0000u), w, acc[5]);
    acc[6] = fmaf(__uint_as_float((unsigned)u.w << 16), w, acc[6]);
    acc[7] = fmaf(__uint_as_float((unsigned)u.w & 0xFFFF0000u), w, acc[7]);
}

// exclusive scan of sd[0..len) in place; sd must have len+1 slots.
__device__ __forceinline__ void lds_excl_scan(int* sd, int len) {
    __syncthreads();
    if (threadIdx.x < 64) {
        int lane = threadIdx.x;
        int carry = 0;
        for (int c0 = 0; c0 < len; c0 += 64) {
            int idx = c0 + lane;
            int v = (idx < len) ? sd[idx] : 0;
            int s = v;
            for (int off = 1; off < 64; off <<= 1) {
                int t = __shfl_up(s, off);
                if (lane >= off) s += t;
            }
            if (idx < len) sd[idx] = carry + s - v;
            carry += __shfl(s, 63);
        }
        if (lane == 0) sd[len] = carry;
    }
    __syncthreads();
}

// ------------------------------------------------- h(bf16) = x@W via MFMA
// single-term bf16: block = 4 waves x 16 rows; W -> LDS bf16 transposed
// [col][136] (pad 8). A-frag: row=lane&15, k=(lane>>4)*8+j. B: col=lane&15.
// C/D: col=lane&15, row=(lane>>4)*4+reg (verified R8).
__global__ __launch_bounds__(256) void k_gemm(
    const float* __restrict__ x, const float* __restrict__ Wg,
    const float* __restrict__ att_s, const float* __restrict__ att_d,
    unsigned short* __restrict__ h2, float* __restrict__ a_src,
    float* __restrict__ a_dst, int n) {
    __shared__ unsigned short Wh[64 * 136];   // 17 KB
    {
        const float4* wg4 = (const float4*)Wg;  // [k=128][col=64] row-major
#pragma unroll
        for (int i = 0; i < 8; ++i) {
            int f = threadIdx.x + i * 256;  // [0, 2048)
            float4 w = wg4[f];
            int k = f >> 4;
            int c0 = (f & 15) << 2;
            Wh[(c0 + 0) * 136 + k] = f2bf(w.x);
            Wh[(c0 + 1) * 136 + k] = f2bf(w.y);
            Wh[(c0 + 2) * 136 + k] = f2bf(w.z);
            Wh[(c0 + 3) * 136 + k] = f2bf(w.w);
        }
    }
    __syncthreads();

    const int lane = threadIdx.x & 63;
    const int wave = threadIdx.x >> 6;
    const int rb = blockIdx.x * 64 + wave * 16;
    const int arow = rb + (lane & 15);
    const int kb = (lane >> 4) << 3;
    const int col = lane & 15;

    f32x4 acc[4];
#pragma unroll
    for (int ct = 0; ct < 4; ++ct) acc[ct] = (f32x4){0.f, 0.f, 0.f, 0.f};

#pragma unroll
    for (int ks = 0; ks < 4; ++ks) {
        const int k0 = ks * 32 + kb;
        float av[8];
        if (arow < n) {
            float4 a0 = *(const float4*)(x + (size_t)arow * 128 + k0);
            float4 a1 = *(const float4*)(x + (size_t)arow * 128 + k0 + 4);
            av[0] = a0.x; av[1] = a0.y; av[2] = a0.z; av[3] = a0.w;
            av[4] = a1.x; av[5] = a1.y; av[6] = a1.z; av[7] = a1.w;
        } else {
#pragma unroll
            for (int j = 0; j < 8; ++j) av[j] = 0.f;
        }
        bf16x8 ah;
#pragma unroll
        for (int j = 0; j < 8; ++j) ah[j] = (short)f2bf(av[j]);
#pragma unroll
        for (int ct = 0; ct < 4; ++ct) {
            const bf16x8 bh = *(const bf16x8*)(&Wh[(ct * 16 + col) * 136 + k0]);
            acc[ct] = __builtin_amdgcn_mfma_f32_16x16x32_bf16(ah, bh, acc[ct], 0, 0, 0);
        }
    }

    float as_f[4], ad_f[4];
#pragma unroll
    for (int ct = 0; ct < 4; ++ct) {
        as_f[ct] = att_s[ct * 16 + col];
        ad_f[ct] = att_d[ct * 16 + col];
    }
#pragma unroll
    for (int reg = 0; reg < 4; ++reg) {
        const int row = rb + ((lane >> 4) << 2) + reg;
        float s = 0.f, t = 0.f;
#pragma unroll
        for (int ct = 0; ct < 4; ++ct) {
            float v = acc[ct][reg];
            s = fmaf(v, as_f[ct], s);
            t = fmaf(v, ad_f[ct], t);
            if (row < n) h2[(size_t)row * 64 + ct * 16 + col] = f2bf(v);
        }
#pragma unroll
        for (int o = 1; o < 16; o <<= 1) {
            s += __shfl_xor(s, o);
            t += __shfl_xor(t, o);
        }
        if (col == 0 && row < n) { a_src[row] = s; a_dst[row] = t; }
    }
}

// ------------------------------------------------- coarse scatter (LDS reorder)
__global__ __launch_bounds__(256) void k_cscatter(
    const int* __restrict__ srcv, const int* __restrict__ dstv,
    int* __restrict__ gcursor, int* __restrict__ words, int e, int nbc) {
    __shared__ int sc[NBC_MAX + 1];
    __shared__ int offs[NBC_MAX];
    __shared__ int gbase[NBC_MAX];
    __shared__ int lim[NBC_MAX];
    __shared__ int2 staged[4096];
    for (int t = threadIdx.x; t < nbc; t += 256) { sc[t] = 0; offs[t] = 0; }
    __syncthreads();
    const int base = blockIdx.x * 4096;
    int s_[16], d_[16];
#pragma unroll
    for (int k = 0; k < 16; ++k) {
        int i = base + k * 256 + threadIdx.x;
        if (i < e) {
            s_[k] = srcv[i];
            d_[k] = dstv[i];
            atomicAdd(&sc[d_[k] >> 8], 1);
        } else {
            d_[k] = -1;
        }
    }
    lds_excl_scan(sc, nbc);
    for (int t = threadIdx.x; t < nbc; t += 256) {
        int c = sc[t + 1] - sc[t];
        if (c) {
            int r0 = atomicAdd(&gcursor[t], c);
            gbase[t] = t * SCAP + r0;
            lim[t] = max(0, SCAP - r0);
        }
    }
    __syncthreads();
#pragma unroll
    for (int k = 0; k < 16; ++k) {
        if (d_[k] >= 0) {
            int b = d_[k] >> 8;
            int r = atomicAdd(&offs[b], 1);
            staged[sc[b] + r] = make_int2(s_[k], d_[k]);
        }
    }
    __syncthreads();
    const int tot = sc[nbc];
    for (int p = threadIdx.x; p < tot; p += 256) {
        int2 pr = staged[p];
        int b = pr.y >> 8;
        int off2 = p - sc[b];
        if (off2 < lim[b]) {
            int word = ((pr.y & 255) << 17) | pr.x;  // dst_low:8 | src:17
            words[gbase[b] + off2] = word;
        }
    }
}

// ------------------------------------------------- fine sort + edge exp
// one block per bucket: counting-sort by dst_low (reads words twice from L2),
// write ewp=(word, exp(leaky(ev))) coalesced + rowptrB (257 entries/bucket).
__global__ __launch_bounds__(256) void k_fsort(
    const int* __restrict__ words, const int* __restrict__ gcursor,
    const float* __restrict__ a_src, const float* __restrict__ a_dst,
    int2* __restrict__ ewp, int* __restrict__ rowptrB, int n) {
    __shared__ int rp[257];
    __shared__ int offs[256];
    __shared__ int sorted_[SCAP];   // 24 KB
    __shared__ float adst_l[256];
    const int b = blockIdx.x;
    const int d0 = b << 8;
    const int ndl = min(256, n - d0);
    const int base = b * SCAP;
    const int cnt = min(gcursor[b], SCAP);
    const int tid = threadIdx.x;
    rp[tid] = 0;
    offs[tid] = 0;
    if (tid == 0) rp[256] = 0;
    if (tid < ndl) adst_l[tid] = a_dst[d0 + tid];
    __syncthreads();
    // histogram (read 1)
    for (int p = tid; p < cnt; p += 256)
        atomicAdd(&rp[(words[base + p] >> 17) & 255], 1);
    lds_excl_scan(rp, 256);
    // reorder into LDS (read 2)
    for (int p = tid; p < cnt; p += 256) {
        int w = words[base + p];
        int dl = (w >> 17) & 255;
        int r = atomicAdd(&offs[dl], 1);
        sorted_[rp[dl] + r] = w;
    }
    __syncthreads();
    // exp pass + coalesced ewp write
    for (int p = tid; p < cnt; p += 256) {
        int w = sorted_[p];
        float al = __expf(leaky(a_src[w & 0x1FFFF] + adst_l[(w >> 17) & 255]));
        ewp[base + p] = make_int2(w, __float_as_int(al));
    }
    for (int t = tid; t <= 256; t += 256)
        rowptrB[b * 257 + t] = base + rp[t];
}

// ------------------------------------------------- weighted gather-aggregate
// wave per dst; lane owns edge (one ewp load / 64 edges), shfl broadcast,
// 8 row groups x 8 features; weight-sum accumulated, single divide at end.
__global__ __launch_bounds__(256) void k_aggr(
    const unsigned short* __restrict__ h2, const float* __restrict__ a_src,
    const float* __restrict__ a_dst, const int* __restrict__ rowptrB,
    const int2* __restrict__ ewp, float* __restrict__ out, int n) {
    const int lane = threadIdx.x & 63;
    int d = (blockIdx.x << 2) + (threadIdx.x >> 6);
    if (d >= n) return;
    d = __builtin_amdgcn_readfirstlane(d);
    const int b = d >> 8;
    const int dl = d & 255;
    const int s0 = rowptrB[b * 257 + dl];
    const int s1 = rowptrB[b * 257 + dl + 1];
    const int deg = s1 - s0;
    const float wself = __expf(leaky(a_src[d] + a_dst[d]));

    const int r = lane >> 3;          // row group 0..7
    const int f0 = (lane & 7) << 3;   // feature octet
    float acc[8] = {0.f, 0.f, 0.f, 0.f, 0.f, 0.f, 0.f, 0.f};
    float wsum_l = 0.f;
    if (r == 0) {  // self loop
        int4 u = *(const int4*)(h2 + (size_t)d * 64 + f0);
        bf8_fma(acc, u, wself);
    }
    for (int cb = 0; cb < deg; cb += 64) {
        int src = 0;
        float w = 0.f;
        int j0 = cb + lane;
        if (j0 < deg) {
            int2 p = ewp[s0 + j0];
            src = p.x & 0x1FFFF;
            w = __int_as_float(p.y);
        }
        wsum_l += w;
        const int cnt = min(64, deg - cb);
        for (int c0 = 0; c0 < cnt; c0 += 8) {
            int j = c0 + r;
            int sj = __shfl(src, j);
            float wj = __shfl(w, j);
            if (j < cnt) {
                int4 u = *(const int4*)(h2 + (size_t)sj * 64 + f0);
                bf8_fma(acc, u, wj);
            }
        }
    }
    const float den = wave_sum(wsum_l) + wself;
    const float inv = 1.0f / (den + 1e-16f);
#pragma unroll
    for (int i = 0; i < 8; ++i) {
        acc[i] += __shfl_xor(acc[i], 8);
        acc[i] += __shfl_xor(acc[i], 16);
        acc[i] += __shfl_xor(acc[i], 32);
    }
    if (lane < 8) {
        float* op = out + (size_t)d * 64 + f0;
        *(float4*)op = make_float4(acc[0] * inv, acc[1] * inv,
                                   acc[2] * inv, acc[3] * inv);
        *(float4*)(op + 4) = make_float4(acc[4] * inv, acc[5] * inv,
                                         acc[6] * inv, acc[7] * inv);
    }
}

extern "C" void kernel_launch(void* const* d_in, const int* in_sizes, int n_in,
                              void* d_out, int out_size, void* d_ws, size_t ws_size,
                              hipStream_t stream) {
    const float* x = (const float*)d_in[0];
    const float* W = (const float*)d_in[1];
    const float* att_s = (const float*)d_in[2];
    const float* att_d = (const float*)d_in[3];
    const int* ei = (const int*)d_in[4];
    const int n = in_sizes[0] / 128;
    const int e = in_sizes[4] / 2;
    const int* srcv = ei;
    const int* dstv = ei + e;
    float* out = (float*)d_out;

    char* ws = (char*)d_ws;
    size_t off = 0;
    auto carve = [&](size_t bytes) -> void* {
        void* p = ws + off;
        off = (off + bytes + 63) & ~(size_t)63;
        return p;
    };
    const int nbc = (n + 255) >> 8;  // coarse buckets (<= NBC_MAX)
    unsigned short* h2 = (unsigned short*)carve((size_t)n * 64 * 2);
    float* a_src  = (float*)carve((size_t)n * 4);
    float* a_dst  = (float*)carve((size_t)n * 4);
    int* gcursor  = (int*)carve((size_t)NBC_MAX * 4);
    int* rowptrB  = (int*)carve((size_t)nbc * 257 * 4);
    int* words    = (int*)carve((size_t)nbc * SCAP * 4);
    int2* ewp     = (int2*)carve((size_t)nbc * SCAP * 8);
    (void)ws_size; (void)n_in; (void)out_size;

    const int neb = (e + 4095) / 4096;

    hipMemsetAsync(gcursor, 0, (size_t)NBC_MAX * 4, stream);

    k_gemm<<<(n + 63) / 64, 256, 0, stream>>>(x, W, att_s, att_d, h2, a_src, a_dst, n);
    k_cscatter<<<neb, 256, 0, stream>>>(srcv, dstv, gcursor, words, e, nbc);
    k_fsort<<<nbc, 256, 0, stream>>>(words, gcursor, a_src, a_dst, ewp, rowptrB, n);
    k_aggr<<<(n + 3) / 4, 256, 0, stream>>>(h2, a_src, a_dst, rowptrB, ewp, out, n);
}

// Round 13
// 102.539 us; speedup vs baseline: 1.3320x; 1.0762x over previous
//
#include <hip/hip_runtime.h>

// GATConv fused pipeline, MI355X.
// R13: k_aggr -> 4 dsts per wave (16 lanes/dst: 2 row-pairs x 8 feat-octets).
//   R12 audit: per-dst fixed cost (24-shuffle epilogue + 6-deep wave_sum +
//   setup) ~= edge-loop cost at deg~16. Now: epilogue = 1 shfl_xor per acc,
//   wsum = 4-step group reduce, fixed cost shared x4, 25K waves (was 100K).
//   Full chunks take fully-unrolled inner body (8 independent loads, ILP).
//   gcursor zeroing folded into k_gemm block 0 (memset dispatch deleted).
// k_gemm single-term bf16 MFMA, cscatter/fsort unchanged from R12.
// word = dst_low:8 | src:17 (n<=131072). rowptrB[b*257+dl] = abs seg starts.

#define NEG_SLOPE 0.2f
#define NBC_MAX 512
#define SCAP 6144

typedef __attribute__((ext_vector_type(8))) short bf16x8;
typedef __attribute__((ext_vector_type(4))) float f32x4;

__device__ __forceinline__ float leaky(float v) {
    return v > 0.f ? v : NEG_SLOPE * v;
}
__device__ __forceinline__ unsigned short f2bf(float f) {
    unsigned b = __float_as_uint(f);
    return (unsigned short)((b + 0x7FFFu + ((b >> 16) & 1u)) >> 16);
}
__device__ __forceinline__ float bf2f(unsigned short u) {
    return __uint_as_float(((unsigned)u) << 16);
}
// fma 8 bf16 features (packed in int4) into acc[8] with weight w
__device__ __forceinline__ void bf8_fma(float* acc, int4 u, float w) {
    acc[0] = fmaf(__uint_as_float((unsigned)u.x << 16), w, acc[0]);
    acc[1] = fmaf(__uint_as_float((unsigned)u.x & 0xFFFF0000u), w, acc[1]);
    acc[2] = fmaf(__uint_as_float((unsigned)u.y << 16), w, acc[2]);
    acc[3] = fmaf(__uint_as_float((unsigned)u.y & 0xFFFF0000u), w, acc[3]);
    acc[4] = fmaf(__uint_as_float((unsigned)u.z << 16), w, acc[4]);
    acc[5] = fmaf(__uint_as_float((unsigned)u.z & 0xFFFF0000u), w, acc[5]);
    acc[6] = fmaf(__uint_as_float((unsigned)u.w << 16), w, acc[6]);
    acc[7] = fmaf(__uint_as_float((unsigned)u.w & 0xFFFF0000u), w, acc[7]);
}

// exclusive scan of sd[0..len) in place; sd must have len+1 slots.
__device__ __forceinline__ void lds_excl_scan(int* sd, int len) {
    __syncthreads();
    if (threadIdx.x < 64) {
        int lane = threadIdx.x;
        int carry = 0;
        for (int c0 = 0; c0 < len; c0 += 64) {
            int idx = c0 + lane;
            int v = (idx < len) ? sd[idx] : 0;
            int s = v;
            for (int off = 1; off < 64; off <<= 1) {
                int t = __shfl_up(s, off);
                if (lane >= off) s += t;
            }
            if (idx < len) sd[idx] = carry + s - v;
            carry += __shfl(s, 63);
        }
        if (lane == 0) sd[len] = carry;
    }
    __syncthreads();
}

// ------------------------------------------------- h(bf16) = x@W via MFMA
// single-term bf16; block 0 also zeroes gcursor (memset dispatch folded in).
__global__ __launch_bounds__(256) void k_gemm(
    const float* __restrict__ x, const float* __restrict__ Wg,
    const float* __restrict__ att_s, const float* __restrict__ att_d,
    unsigned short* __restrict__ h2, float* __restrict__ a_src,
    float* __restrict__ a_dst, int* __restrict__ gcursor, int n) {
    if (blockIdx.x == 0) {
        gcursor[threadIdx.x] = 0;
        gcursor[256 + threadIdx.x] = 0;
    }
    __shared__ unsigned short Wh[64 * 136];   // 17 KB
    {
        const float4* wg4 = (const float4*)Wg;  // [k=128][col=64] row-major
#pragma unroll
        for (int i = 0; i < 8; ++i) {
            int f = threadIdx.x + i * 256;  // [0, 2048)
            float4 w = wg4[f];
            int k = f >> 4;
            int c0 = (f & 15) << 2;
            Wh[(c0 + 0) * 136 + k] = f2bf(w.x);
            Wh[(c0 + 1) * 136 + k] = f2bf(w.y);
            Wh[(c0 + 2) * 136 + k] = f2bf(w.z);
            Wh[(c0 + 3) * 136 + k] = f2bf(w.w);
        }
    }
    __syncthreads();

    const int lane = threadIdx.x & 63;
    const int wave = threadIdx.x >> 6;
    const int rb = blockIdx.x * 64 + wave * 16;
    const int arow = rb + (lane & 15);
    const int kb = (lane >> 4) << 3;
    const int col = lane & 15;

    f32x4 acc[4];
#pragma unroll
    for (int ct = 0; ct < 4; ++ct) acc[ct] = (f32x4){0.f, 0.f, 0.f, 0.f};

#pragma unroll
    for (int ks = 0; ks < 4; ++ks) {
        const int k0 = ks * 32 + kb;
        float av[8];
        if (arow < n) {
            float4 a0 = *(const float4*)(x + (size_t)arow * 128 + k0);
            float4 a1 = *(const float4*)(x + (size_t)arow * 128 + k0 + 4);
            av[0] = a0.x; av[1] = a0.y; av[2] = a0.z; av[3] = a0.w;
            av[4] = a1.x; av[5] = a1.y; av[6] = a1.z; av[7] = a1.w;
        } else {
#pragma unroll
            for (int j = 0; j < 8; ++j) av[j] = 0.f;
        }
        bf16x8 ah;
#pragma unroll
        for (int j = 0; j < 8; ++j) ah[j] = (short)f2bf(av[j]);
#pragma unroll
        for (int ct = 0; ct < 4; ++ct) {
            const bf16x8 bh = *(const bf16x8*)(&Wh[(ct * 16 + col) * 136 + k0]);
            acc[ct] = __builtin_amdgcn_mfma_f32_16x16x32_bf16(ah, bh, acc[ct], 0, 0, 0);
        }
    }

    float as_f[4], ad_f[4];
#pragma unroll
    for (int ct = 0; ct < 4; ++ct) {
        as_f[ct] = att_s[ct * 16 + col];
        ad_f[ct] = att_d[ct * 16 + col];
    }
#pragma unroll
    for (int reg = 0; reg < 4; ++reg) {
        const int row = rb + ((lane >> 4) << 2) + reg;
        float s = 0.f, t = 0.f;
#pragma unroll
        for (int ct = 0; ct < 4; ++ct) {
            float v = acc[ct][reg];
            s = fmaf(v, as_f[ct], s);
            t = fmaf(v, ad_f[ct], t);
            if (row < n) h2[(size_t)row * 64 + ct * 16 + col] = f2bf(v);
        }
#pragma unroll
        for (int o = 1; o < 16; o <<= 1) {
            s += __shfl_xor(s, o);
            t += __shfl_xor(t, o);
        }
        if (col == 0 && row < n) { a_src[row] = s; a_dst[row] = t; }
    }
}

// ------------------------------------------------- coarse scatter (LDS reorder)
__global__ __launch_bounds__(256) void k_cscatter(
    const int* __restrict__ srcv, const int* __restrict__ dstv,
    int* __restrict__ gcursor, int* __restrict__ words, int e, int nbc) {
    __shared__ int sc[NBC_MAX + 1];
    __shared__ int offs[NBC_MAX];
    __shared__ int gbase[NBC_MAX];
    __shared__ int lim[NBC_MAX];
    __shared__ int2 staged[4096];
    for (int t = threadIdx.x; t < nbc; t += 256) { sc[t] = 0; offs[t] = 0; }
    __syncthreads();
    const int base = blockIdx.x * 4096;
    int s_[16], d_[16];
#pragma unroll
    for (int k = 0; k < 16; ++k) {
        int i = base + k * 256 + threadIdx.x;
        if (i < e) {
            s_[k] = srcv[i];
            d_[k] = dstv[i];
            atomicAdd(&sc[d_[k] >> 8], 1);
        } else {
            d_[k] = -1;
        }
    }
    lds_excl_scan(sc, nbc);
    for (int t = threadIdx.x; t < nbc; t += 256) {
        int c = sc[t + 1] - sc[t];
        if (c) {
            int r0 = atomicAdd(&gcursor[t], c);
            gbase[t] = t * SCAP + r0;
            lim[t] = max(0, SCAP - r0);
        }
    }
    __syncthreads();
#pragma unroll
    for (int k = 0; k < 16; ++k) {
        if (d_[k] >= 0) {
            int b = d_[k] >> 8;
            int r = atomicAdd(&offs[b], 1);
            staged[sc[b] + r] = make_int2(s_[k], d_[k]);
        }
    }
    __syncthreads();
    const int tot = sc[nbc];
    for (int p = threadIdx.x; p < tot; p += 256) {
        int2 pr = staged[p];
        int b = pr.y >> 8;
        int off2 = p - sc[b];
        if (off2 < lim[b]) {
            int word = ((pr.y & 255) << 17) | pr.x;  // dst_low:8 | src:17
            words[gbase[b] + off2] = word;
        }
    }
}

// ------------------------------------------------- fine sort + edge exp
__global__ __launch_bounds__(256) void k_fsort(
    const int* __restrict__ words, const int* __restrict__ gcursor,
    const float* __restrict__ a_src, const float* __restrict__ a_dst,
    int2* __restrict__ ewp, int* __restrict__ rowptrB, int n) {
    __shared__ int rp[257];
    __shared__ int offs[256];
    __shared__ int sorted_[SCAP];   // 24 KB
    __shared__ float adst_l[256];
    const int b = blockIdx.x;
    const int d0 = b << 8;
    const int ndl = min(256, n - d0);
    const int base = b * SCAP;
    const int cnt = min(gcursor[b], SCAP);
    const int tid = threadIdx.x;
    rp[tid] = 0;
    offs[tid] = 0;
    if (tid == 0) rp[256] = 0;
    if (tid < ndl) adst_l[tid] = a_dst[d0 + tid];
    __syncthreads();
    for (int p = tid; p < cnt; p += 256)
        atomicAdd(&rp[(words[base + p] >> 17) & 255], 1);
    lds_excl_scan(rp, 256);
    for (int p = tid; p < cnt; p += 256) {
        int w = words[base + p];
        int dl = (w >> 17) & 255;
        int r = atomicAdd(&offs[dl], 1);
        sorted_[rp[dl] + r] = w;
    }
    __syncthreads();
    for (int p = tid; p < cnt; p += 256) {
        int w = sorted_[p];
        float al = __expf(leaky(a_src[w & 0x1FFFF] + adst_l[(w >> 17) & 255]));
        ewp[base + p] = make_int2(w, __float_as_int(al));
    }
    for (int t = tid; t <= 256; t += 256)
        rowptrB[b * 257 + t] = base + rp[t];
}

// ------------------------------------------------- weighted gather-aggregate
// 4 dsts per wave: 16 lanes/dst = 2 row-pairs x 8 feature-octets.
// chunk = 16 edges/dst (one ewp load per lane); full chunks fully unrolled.
__global__ __launch_bounds__(256) void k_aggr(
    const unsigned short* __restrict__ h2, const float* __restrict__ a_src,
    const float* __restrict__ a_dst, const int* __restrict__ rowptrB,
    const int2* __restrict__ ewp, float* __restrict__ out, int n) {
    const int lane = threadIdx.x & 63;
    const int wave = threadIdx.x >> 6;
    const int d = blockIdx.x * 16 + wave * 4 + (lane >> 4);
    if (d >= n) return;
    const int b = d >> 8;
    const int dl = d & 255;
    const int s0 = rowptrB[b * 257 + dl];
    const int deg = rowptrB[b * 257 + dl + 1] - s0;
    const float wself = __expf(leaky(a_src[d] + a_dst[d]));

    const int r = (lane >> 3) & 1;    // row pair 0/1
    const int f0 = (lane & 7) << 3;   // feature octet
    const int gb = lane & 48;         // group base lane
    float acc[8] = {0.f, 0.f, 0.f, 0.f, 0.f, 0.f, 0.f, 0.f};
    float wsum_l = 0.f;
    if (r == 0) {  // self loop
        int4 u = *(const int4*)(h2 + (size_t)d * 64 + f0);
        bf8_fma(acc, u, wself);
    }
    for (int cb = 0; cb < deg; cb += 16) {
        int src = 0;
        float w = 0.f;
        int j0 = cb + (lane & 15);
        if (j0 < deg) {
            int2 p = ewp[s0 + j0];
            src = p.x & 0x1FFFF;
            w = __int_as_float(p.y);
        }
        wsum_l += w;
        const int cnt = min(16, deg - cb);
        if (cnt == 16) {
#pragma unroll
            for (int c0 = 0; c0 < 16; c0 += 2) {
                int sl = gb | (c0 + r);
                int sj = __shfl(src, sl);
                float wj = __shfl(w, sl);
                int4 u = *(const int4*)(h2 + (size_t)sj * 64 + f0);
                bf8_fma(acc, u, wj);
            }
        } else {
            for (int c0 = 0; c0 < cnt; c0 += 2) {
                int j = c0 + r;
                int sj = __shfl(src, gb | j);
                float wj = __shfl(w, gb | j);
                if (j < cnt) {
                    int4 u = *(const int4*)(h2 + (size_t)sj * 64 + f0);
                    bf8_fma(acc, u, wj);
                }
            }
        }
    }
    // wsum over the 16-lane group
#pragma unroll
    for (int o = 8; o >= 1; o >>= 1) wsum_l += __shfl_xor(wsum_l, o);
    const float inv = 1.0f / (wsum_l + wself + 1e-16f);
    // combine row pairs
#pragma unroll
    for (int i = 0; i < 8; ++i) acc[i] += __shfl_xor(acc[i], 8);
    if (r == 0) {
        float* op = out + (size_t)d * 64 + f0;
        *(float4*)op = make_float4(acc[0] * inv, acc[1] * inv,
                                   acc[2] * inv, acc[3] * inv);
        *(float4*)(op + 4) = make_float4(acc[4] * inv, acc[5] * inv,
                                         acc[6] * inv, acc[7] * inv);
    }
}

extern "C" void kernel_launch(void* const* d_in, const int* in_sizes, int n_in,
                              void* d_out, int out_size, void* d_ws, size_t ws_size,
                              hipStream_t stream) {
    const float* x = (const float*)d_in[0];
    const float* W = (const float*)d_in[1];
    const float* att_s = (const float*)d_in[2];
    const float* att_d = (const float*)d_in[3];
    const int* ei = (const int*)d_in[4];
    const int n = in_sizes[0] / 128;
    const int e = in_sizes[4] / 2;
    const int* srcv = ei;
    const int* dstv = ei + e;
    float* out = (float*)d_out;

    char* ws = (char*)d_ws;
    size_t off = 0;
    auto carve = [&](size_t bytes) -> void* {
        void* p = ws + off;
        off = (off + bytes + 63) & ~(size_t)63;
        return p;
    };
    const int nbc = (n + 255) >> 8;  // coarse buckets (<= NBC_MAX)
    unsigned short* h2 = (unsigned short*)carve((size_t)n * 64 * 2);
    float* a_src  = (float*)carve((size_t)n * 4);
    float* a_dst  = (float*)carve((size_t)n * 4);
    int* gcursor  = (int*)carve((size_t)NBC_MAX * 4);
    int* rowptrB  = (int*)carve((size_t)nbc * 257 * 4);
    int* words    = (int*)carve((size_t)nbc * SCAP * 4);
    int2* ewp     = (int2*)carve((size_t)nbc * SCAP * 8);
    (void)ws_size; (void)n_in; (void)out_size;

    const int neb = (e + 4095) / 4096;

    k_gemm<<<(n + 63) / 64, 256, 0, stream>>>(x, W, att_s, att_d, h2, a_src,
                                              a_dst, gcursor, n);
    k_cscatter<<<neb, 256, 0, stream>>>(srcv, dstv, gcursor, words, e, nbc);
    k_fsort<<<nbc, 256, 0, stream>>>(words, gcursor, a_src, a_dst, ewp, rowptrB, n);
    k_aggr<<<(n + 15) / 16, 256, 0, stream>>>(h2, a_src, a_dst, rowptrB, ewp, out, n);
}

// Round 14
// 93.652 us; speedup vs baseline: 1.4584x; 1.0949x over previous
//
#include <hip/hip_runtime.h>

// GATConv fused pipeline, MI355X.
// R14: k_aggr chunk widened 16->32 edges (two guarded int2 ewp loads/lane
//   issued together): chunk loop = 1 iteration for ~all waves (Poisson(16),
//   P(maxdeg4>32)~0) -> one ewp latency instead of two serialized, 16
//   independent h2 gathers in flight per group. R13 was latency-bound
//   (VALU 34%, HBM 32%, 2 chunks x 2 serialized latencies).
// k_gemm single-term bf16 MFMA, cscatter/fsort unchanged from R13.
// word = dst_low:8 | src:17 (n<=131072). rowptrB[b*257+dl] = abs seg starts.

#define NEG_SLOPE 0.2f
#define NBC_MAX 512
#define SCAP 6144

typedef __attribute__((ext_vector_type(8))) short bf16x8;
typedef __attribute__((ext_vector_type(4))) float f32x4;

__device__ __forceinline__ float leaky(float v) {
    return v > 0.f ? v : NEG_SLOPE * v;
}
__device__ __forceinline__ unsigned short f2bf(float f) {
    unsigned b = __float_as_uint(f);
    return (unsigned short)((b + 0x7FFFu + ((b >> 16) & 1u)) >> 16);
}
__device__ __forceinline__ float bf2f(unsigned short u) {
    return __uint_as_float(((unsigned)u) << 16);
}
// fma 8 bf16 features (packed in int4) into acc[8] with weight w
__device__ __forceinline__ void bf8_fma(float* acc, int4 u, float w) {
    acc[0] = fmaf(__uint_as_float((unsigned)u.x << 16), w, acc[0]);
    acc[1] = fmaf(__uint_as_float((unsigned)u.x & 0xFFFF0000u), w, acc[1]);
    acc[2] = fmaf(__uint_as_float((unsigned)u.y << 16), w, acc[2]);
    acc[3] = fmaf(__uint_as_float((unsigned)u.y & 0xFFFF0000u), w, acc[3]);
    acc[4] = fmaf(__uint_as_float((unsigned)u.z << 16), w, acc[4]);
    acc[5] = fmaf(__uint_as_float((unsigned)u.z & 0xFFFF0000u), w, acc[5]);
    acc[6] = fmaf(__uint_as_float((unsigned)u.w << 16), w, acc[6]);
    acc[7] = fmaf(__uint_as_float((unsigned)u.w & 0xFFFF0000u), w, acc[7]);
}

// exclusive scan of sd[0..len) in place; sd must have len+1 slots.
__device__ __forceinline__ void lds_excl_scan(int* sd, int len) {
    __syncthreads();
    if (threadIdx.x < 64) {
        int lane = threadIdx.x;
        int carry = 0;
        for (int c0 = 0; c0 < len; c0 += 64) {
            int idx = c0 + lane;
            int v = (idx < len) ? sd[idx] : 0;
            int s = v;
            for (int off = 1; off < 64; off <<= 1) {
                int t = __shfl_up(s, off);
                if (lane >= off) s += t;
            }
            if (idx < len) sd[idx] = carry + s - v;
            carry += __shfl(s, 63);
        }
        if (lane == 0) sd[len] = carry;
    }
    __syncthreads();
}

// ------------------------------------------------- h(bf16) = x@W via MFMA
// single-term bf16; block 0 also zeroes gcursor (memset dispatch folded in).
__global__ __launch_bounds__(256) void k_gemm(
    const float* __restrict__ x, const float* __restrict__ Wg,
    const float* __restrict__ att_s, const float* __restrict__ att_d,
    unsigned short* __restrict__ h2, float* __restrict__ a_src,
    float* __restrict__ a_dst, int* __restrict__ gcursor, int n) {
    if (blockIdx.x == 0) {
        gcursor[threadIdx.x] = 0;
        gcursor[256 + threadIdx.x] = 0;
    }
    __shared__ unsigned short Wh[64 * 136];   // 17 KB
    {
        const float4* wg4 = (const float4*)Wg;  // [k=128][col=64] row-major
#pragma unroll
        for (int i = 0; i < 8; ++i) {
            int f = threadIdx.x + i * 256;  // [0, 2048)
            float4 w = wg4[f];
            int k = f >> 4;
            int c0 = (f & 15) << 2;
            Wh[(c0 + 0) * 136 + k] = f2bf(w.x);
            Wh[(c0 + 1) * 136 + k] = f2bf(w.y);
            Wh[(c0 + 2) * 136 + k] = f2bf(w.z);
            Wh[(c0 + 3) * 136 + k] = f2bf(w.w);
        }
    }
    __syncthreads();

    const int lane = threadIdx.x & 63;
    const int wave = threadIdx.x >> 6;
    const int rb = blockIdx.x * 64 + wave * 16;
    const int arow = rb + (lane & 15);
    const int kb = (lane >> 4) << 3;
    const int col = lane & 15;

    f32x4 acc[4];
#pragma unroll
    for (int ct = 0; ct < 4; ++ct) acc[ct] = (f32x4){0.f, 0.f, 0.f, 0.f};

#pragma unroll
    for (int ks = 0; ks < 4; ++ks) {
        const int k0 = ks * 32 + kb;
        float av[8];
        if (arow < n) {
            float4 a0 = *(const float4*)(x + (size_t)arow * 128 + k0);
            float4 a1 = *(const float4*)(x + (size_t)arow * 128 + k0 + 4);
            av[0] = a0.x; av[1] = a0.y; av[2] = a0.z; av[3] = a0.w;
            av[4] = a1.x; av[5] = a1.y; av[6] = a1.z; av[7] = a1.w;
        } else {
#pragma unroll
            for (int j = 0; j < 8; ++j) av[j] = 0.f;
        }
        bf16x8 ah;
#pragma unroll
        for (int j = 0; j < 8; ++j) ah[j] = (short)f2bf(av[j]);
#pragma unroll
        for (int ct = 0; ct < 4; ++ct) {
            const bf16x8 bh = *(const bf16x8*)(&Wh[(ct * 16 + col) * 136 + k0]);
            acc[ct] = __builtin_amdgcn_mfma_f32_16x16x32_bf16(ah, bh, acc[ct], 0, 0, 0);
        }
    }

    float as_f[4], ad_f[4];
#pragma unroll
    for (int ct = 0; ct < 4; ++ct) {
        as_f[ct] = att_s[ct * 16 + col];
        ad_f[ct] = att_d[ct * 16 + col];
    }
#pragma unroll
    for (int reg = 0; reg < 4; ++reg) {
        const int row = rb + ((lane >> 4) << 2) + reg;
        float s = 0.f, t = 0.f;
#pragma unroll
        for (int ct = 0; ct < 4; ++ct) {
            float v = acc[ct][reg];
            s = fmaf(v, as_f[ct], s);
            t = fmaf(v, ad_f[ct], t);
            if (row < n) h2[(size_t)row * 64 + ct * 16 + col] = f2bf(v);
        }
#pragma unroll
        for (int o = 1; o < 16; o <<= 1) {
            s += __shfl_xor(s, o);
            t += __shfl_xor(t, o);
        }
        if (col == 0 && row < n) { a_src[row] = s; a_dst[row] = t; }
    }
}

// ------------------------------------------------- coarse scatter (LDS reorder)
__global__ __launch_bounds__(256) void k_cscatter(
    const int* __restrict__ srcv, const int* __restrict__ dstv,
    int* __restrict__ gcursor, int* __restrict__ words, int e, int nbc) {
    __shared__ int sc[NBC_MAX + 1];
    __shared__ int offs[NBC_MAX];
    __shared__ int gbase[NBC_MAX];
    __shared__ int lim[NBC_MAX];
    __shared__ int2 staged[4096];
    for (int t = threadIdx.x; t < nbc; t += 256) { sc[t] = 0; offs[t] = 0; }
    __syncthreads();
    const int base = blockIdx.x * 4096;
    int s_[16], d_[16];
#pragma unroll
    for (int k = 0; k < 16; ++k) {
        int i = base + k * 256 + threadIdx.x;
        if (i < e) {
            s_[k] = srcv[i];
            d_[k] = dstv[i];
            atomicAdd(&sc[d_[k] >> 8], 1);
        } else {
            d_[k] = -1;
        }
    }
    lds_excl_scan(sc, nbc);
    for (int t = threadIdx.x; t < nbc; t += 256) {
        int c = sc[t + 1] - sc[t];
        if (c) {
            int r0 = atomicAdd(&gcursor[t], c);
            gbase[t] = t * SCAP + r0;
            lim[t] = max(0, SCAP - r0);
        }
    }
    __syncthreads();
#pragma unroll
    for (int k = 0; k < 16; ++k) {
        if (d_[k] >= 0) {
            int b = d_[k] >> 8;
            int r = atomicAdd(&offs[b], 1);
            staged[sc[b] + r] = make_int2(s_[k], d_[k]);
        }
    }
    __syncthreads();
    const int tot = sc[nbc];
    for (int p = threadIdx.x; p < tot; p += 256) {
        int2 pr = staged[p];
        int b = pr.y >> 8;
        int off2 = p - sc[b];
        if (off2 < lim[b]) {
            int word = ((pr.y & 255) << 17) | pr.x;  // dst_low:8 | src:17
            words[gbase[b] + off2] = word;
        }
    }
}

// ------------------------------------------------- fine sort + edge exp
__global__ __launch_bounds__(256) void k_fsort(
    const int* __restrict__ words, const int* __restrict__ gcursor,
    const float* __restrict__ a_src, const float* __restrict__ a_dst,
    int2* __restrict__ ewp, int* __restrict__ rowptrB, int n) {
    __shared__ int rp[257];
    __shared__ int offs[256];
    __shared__ int sorted_[SCAP];   // 24 KB
    __shared__ float adst_l[256];
    const int b = blockIdx.x;
    const int d0 = b << 8;
    const int ndl = min(256, n - d0);
    const int base = b * SCAP;
    const int cnt = min(gcursor[b], SCAP);
    const int tid = threadIdx.x;
    rp[tid] = 0;
    offs[tid] = 0;
    if (tid == 0) rp[256] = 0;
    if (tid < ndl) adst_l[tid] = a_dst[d0 + tid];
    __syncthreads();
    for (int p = tid; p < cnt; p += 256)
        atomicAdd(&rp[(words[base + p] >> 17) & 255], 1);
    lds_excl_scan(rp, 256);
    for (int p = tid; p < cnt; p += 256) {
        int w = words[base + p];
        int dl = (w >> 17) & 255;
        int r = atomicAdd(&offs[dl], 1);
        sorted_[rp[dl] + r] = w;
    }
    __syncthreads();
    for (int p = tid; p < cnt; p += 256) {
        int w = sorted_[p];
        float al = __expf(leaky(a_src[w & 0x1FFFF] + adst_l[(w >> 17) & 255]));
        ewp[base + p] = make_int2(w, __float_as_int(al));
    }
    for (int t = tid; t <= 256; t += 256)
        rowptrB[b * 257 + t] = base + rp[t];
}

// ------------------------------------------------- weighted gather-aggregate
// 4 dsts per wave (16 lanes/dst: 2 row-pairs x 8 feat-octets).
// 32-edge chunks: 2 guarded int2 ewp loads/lane issued together -> single
// chunk iteration for ~all waves; 16 independent h2 gathers per group.
__global__ __launch_bounds__(256) void k_aggr(
    const unsigned short* __restrict__ h2, const float* __restrict__ a_src,
    const float* __restrict__ a_dst, const int* __restrict__ rowptrB,
    const int2* __restrict__ ewp, float* __restrict__ out, int n) {
    const int lane = threadIdx.x & 63;
    const int wave = threadIdx.x >> 6;
    const int d = blockIdx.x * 16 + wave * 4 + (lane >> 4);
    if (d >= n) return;
    const int b = d >> 8;
    const int dl = d & 255;
    const int s0 = rowptrB[b * 257 + dl];
    const int deg = rowptrB[b * 257 + dl + 1] - s0;
    const float wself = __expf(leaky(a_src[d] + a_dst[d]));

    const int r = (lane >> 3) & 1;    // row pair 0/1
    const int f0 = (lane & 7) << 3;   // feature octet
    const int gb = lane & 48;         // group base lane
    const int lane15 = lane & 15;
    float acc[8] = {0.f, 0.f, 0.f, 0.f, 0.f, 0.f, 0.f, 0.f};
    float wsum_l = 0.f;
    if (r == 0) {  // self loop
        int4 u = *(const int4*)(h2 + (size_t)d * 64 + f0);
        bf8_fma(acc, u, wself);
    }
    for (int cb = 0; cb < deg; cb += 32) {
        const int jA = cb + lane15;
        const int jB = jA + 16;
        int2 pA = make_int2(0, 0), pB = make_int2(0, 0);
        if (jA < deg) pA = ewp[s0 + jA];
        if (jB < deg) pB = ewp[s0 + jB];
        const int srcA = pA.x & 0x1FFFF;
        const float wA = __int_as_float(pA.y);
        const int srcB = pB.x & 0x1FFFF;
        const float wB = __int_as_float(pB.y);
        wsum_l += wA + wB;
        const int cnt = min(32, deg - cb);
#pragma unroll
        for (int c0 = 0; c0 < 16; c0 += 2) {
            const int sl = gb | (c0 + r);
            int sjA = __shfl(srcA, sl);
            float wjA = __shfl(wA, sl);
            int sjB = __shfl(srcB, sl);
            float wjB = __shfl(wB, sl);
            if (c0 + r < cnt) {
                int4 u = *(const int4*)(h2 + (size_t)sjA * 64 + f0);
                bf8_fma(acc, u, wjA);
            }
            if (16 + c0 + r < cnt) {
                int4 u = *(const int4*)(h2 + (size_t)sjB * 64 + f0);
                bf8_fma(acc, u, wjB);
            }
        }
    }
    // wsum over the 16-lane group
#pragma unroll
    for (int o = 8; o >= 1; o >>= 1) wsum_l += __shfl_xor(wsum_l, o);
    const float inv = 1.0f / (wsum_l + wself + 1e-16f);
    // combine row pairs
#pragma unroll
    for (int i = 0; i < 8; ++i) acc[i] += __shfl_xor(acc[i], 8);
    if (r == 0) {
        float* op = out + (size_t)d * 64 + f0;
        *(float4*)op = make_float4(acc[0] * inv, acc[1] * inv,
                                   acc[2] * inv, acc[3] * inv);
        *(float4*)(op + 4) = make_float4(acc[4] * inv, acc[5] * inv,
                                         acc[6] * inv, acc[7] * inv);
    }
}

extern "C" void kernel_launch(void* const* d_in, const int* in_sizes, int n_in,
                              void* d_out, int out_size, void* d_ws, size_t ws_size,
                              hipStream_t stream) {
    const float* x = (const float*)d_in[0];
    const float* W = (const float*)d_in[1];
    const float* att_s = (const float*)d_in[2];
    const float* att_d = (const float*)d_in[3];
    const int* ei = (const int*)d_in[4];
    const int n = in_sizes[0] / 128;
    const int e = in_sizes[4] / 2;
    const int* srcv = ei;
    const int* dstv = ei + e;
    float* out = (float*)d_out;

    char* ws = (char*)d_ws;
    size_t off = 0;
    auto carve = [&](size_t bytes) -> void* {
        void* p = ws + off;
        off = (off + bytes + 63) & ~(size_t)63;
        return p;
    };
    const int nbc = (n + 255) >> 8;  // coarse buckets (<= NBC_MAX)
    unsigned short* h2 = (unsigned short*)carve((size_t)n * 64 * 2);
    float* a_src  = (float*)carve((size_t)n * 4);
    float* a_dst  = (float*)carve((size_t)n * 4);
    int* gcursor  = (int*)carve((size_t)NBC_MAX * 4);
    int* rowptrB  = (int*)carve((size_t)nbc * 257 * 4);
    int* words    = (int*)carve((size_t)nbc * SCAP * 4);
    int2* ewp     = (int2*)carve((size_t)nbc * SCAP * 8);
    (void)ws_size; (void)n_in; (void)out_size;

    const int neb = (e + 4095) / 4096;

    k_gemm<<<(n + 63) / 64, 256, 0, stream>>>(x, W, att_s, att_d, h2, a_src,
                                              a_dst, gcursor, n);
    k_cscatter<<<neb, 256, 0, stream>>>(srcv, dstv, gcursor, words, e, nbc);
    k_fsort<<<nbc, 256, 0, stream>>>(words, gcursor, a_src, a_dst, ewp, rowptrB, n);
    k_aggr<<<(n + 15) / 16, 256, 0, stream>>>(h2, a_src, a_dst, rowptrB, ewp, out, n);
}

// Round 15
// 91.356 us; speedup vs baseline: 1.4950x; 1.0251x over previous
//
#include <hip/hip_runtime.h>

// GATConv fused pipeline, MI355X.
// R15: k_gemm + k_cscatter FUSED into one dispatch (zero data dependence;
//   block-split grid: [0,G) = gemm path, rest = scatter path) -> phases
//   overlap across CUs, cost ~ max instead of sum. LDS union: staged[4096]
//   (32KB) aliases gemm's Wh (17.4KB); lim[] dropped (guard from gbase);
//   scatter edge loads vectorized int4. gcursor zeroed by 2KB memset
//   (gemm-block-0 zeroing would race with concurrent scatter blocks).
// fsort/aggr unchanged from R14 (aggr: 4 dst/wave, 32-edge chunks).
// word = dst_low:8 | src:17 (n<=131072). rowptrB[b*257+dl] = abs seg starts.

#define NEG_SLOPE 0.2f
#define NBC_MAX 512
#define SCAP 6144

typedef __attribute__((ext_vector_type(8))) short bf16x8;
typedef __attribute__((ext_vector_type(4))) float f32x4;

__device__ __forceinline__ float leaky(float v) {
    return v > 0.f ? v : NEG_SLOPE * v;
}
__device__ __forceinline__ unsigned short f2bf(float f) {
    unsigned b = __float_as_uint(f);
    return (unsigned short)((b + 0x7FFFu + ((b >> 16) & 1u)) >> 16);
}
__device__ __forceinline__ float bf2f(unsigned short u) {
    return __uint_as_float(((unsigned)u) << 16);
}
// fma 8 bf16 features (packed in int4) into acc[8] with weight w
__device__ __forceinline__ void bf8_fma(float* acc, int4 u, float w) {
    acc[0] = fmaf(__uint_as_float((unsigned)u.x << 16), w, acc[0]);
    acc[1] = fmaf(__uint_as_float((unsigned)u.x & 0xFFFF0000u), w, acc[1]);
    acc[2] = fmaf(__uint_as_float((unsigned)u.y << 16), w, acc[2]);
    acc[3] = fmaf(__uint_as_float((unsigned)u.y & 0xFFFF0000u), w, acc[3]);
    acc[4] = fmaf(__uint_as_float((unsigned)u.z << 16), w, acc[4]);
    acc[5] = fmaf(__uint_as_float((unsigned)u.z & 0xFFFF0000u), w, acc[5]);
    acc[6] = fmaf(__uint_as_float((unsigned)u.w << 16), w, acc[6]);
    acc[7] = fmaf(__uint_as_float((unsigned)u.w & 0xFFFF0000u), w, acc[7]);
}

// exclusive scan of sd[0..len) in place; sd must have len+1 slots.
__device__ __forceinline__ void lds_excl_scan(int* sd, int len) {
    __syncthreads();
    if (threadIdx.x < 64) {
        int lane = threadIdx.x;
        int carry = 0;
        for (int c0 = 0; c0 < len; c0 += 64) {
            int idx = c0 + lane;
            int v = (idx < len) ? sd[idx] : 0;
            int s = v;
            for (int off = 1; off < 64; off <<= 1) {
                int t = __shfl_up(s, off);
                if (lane >= off) s += t;
            }
            if (idx < len) sd[idx] = carry + s - v;
            carry += __shfl(s, 63);
        }
        if (lane == 0) sd[len] = carry;
    }
    __syncthreads();
}

// ------------------------------------------------- fused gemm | cscatter
// blocks [0, gB): h(bf16)=x@W via single-term bf16 MFMA + a_src/a_dst.
// blocks [gB, gB+neb): coarse scatter (LDS reorder, int4 edge loads).
__global__ __launch_bounds__(256) void k_fused(
    const float* __restrict__ x, const float* __restrict__ Wg,
    const float* __restrict__ att_s, const float* __restrict__ att_d,
    unsigned short* __restrict__ h2, float* __restrict__ a_src,
    float* __restrict__ a_dst,
    const int* __restrict__ srcv, const int* __restrict__ dstv,
    int* __restrict__ gcursor, int* __restrict__ words,
    int n, int e, int nbc, int gB) {
    __shared__ int2 staged[4096];        // 32 KB (gemm: aliased as Wh)
    __shared__ int meta[NBC_MAX * 3 + 1];  // sc | offs | gbase

    if ((int)blockIdx.x < gB) {
        // ---------------- gemm path ----------------
        unsigned short* Wh = (unsigned short*)staged;  // [col][136], 17.4 KB
        {
            const float4* wg4 = (const float4*)Wg;  // [k=128][col=64]
#pragma unroll
            for (int i = 0; i < 8; ++i) {
                int f = threadIdx.x + i * 256;
                float4 w = wg4[f];
                int k = f >> 4;
                int c0 = (f & 15) << 2;
                Wh[(c0 + 0) * 136 + k] = f2bf(w.x);
                Wh[(c0 + 1) * 136 + k] = f2bf(w.y);
                Wh[(c0 + 2) * 136 + k] = f2bf(w.z);
                Wh[(c0 + 3) * 136 + k] = f2bf(w.w);
            }
        }
        __syncthreads();

        const int lane = threadIdx.x & 63;
        const int wave = threadIdx.x >> 6;
        const int rb = blockIdx.x * 64 + wave * 16;
        const int arow = rb + (lane & 15);
        const int kb = (lane >> 4) << 3;
        const int col = lane & 15;

        f32x4 acc[4];
#pragma unroll
        for (int ct = 0; ct < 4; ++ct) acc[ct] = (f32x4){0.f, 0.f, 0.f, 0.f};

#pragma unroll
        for (int ks = 0; ks < 4; ++ks) {
            const int k0 = ks * 32 + kb;
            float av[8];
            if (arow < n) {
                float4 a0 = *(const float4*)(x + (size_t)arow * 128 + k0);
                float4 a1 = *(const float4*)(x + (size_t)arow * 128 + k0 + 4);
                av[0] = a0.x; av[1] = a0.y; av[2] = a0.z; av[3] = a0.w;
                av[4] = a1.x; av[5] = a1.y; av[6] = a1.z; av[7] = a1.w;
            } else {
#pragma unroll
                for (int j = 0; j < 8; ++j) av[j] = 0.f;
            }
            bf16x8 ah;
#pragma unroll
            for (int j = 0; j < 8; ++j) ah[j] = (short)f2bf(av[j]);
#pragma unroll
            for (int ct = 0; ct < 4; ++ct) {
                const bf16x8 bh = *(const bf16x8*)(&Wh[(ct * 16 + col) * 136 + k0]);
                acc[ct] = __builtin_amdgcn_mfma_f32_16x16x32_bf16(ah, bh, acc[ct], 0, 0, 0);
            }
        }

        float as_f[4], ad_f[4];
#pragma unroll
        for (int ct = 0; ct < 4; ++ct) {
            as_f[ct] = att_s[ct * 16 + col];
            ad_f[ct] = att_d[ct * 16 + col];
        }
#pragma unroll
        for (int reg = 0; reg < 4; ++reg) {
            const int row = rb + ((lane >> 4) << 2) + reg;
            float s = 0.f, t = 0.f;
#pragma unroll
            for (int ct = 0; ct < 4; ++ct) {
                float v = acc[ct][reg];
                s = fmaf(v, as_f[ct], s);
                t = fmaf(v, ad_f[ct], t);
                if (row < n) h2[(size_t)row * 64 + ct * 16 + col] = f2bf(v);
            }
#pragma unroll
            for (int o = 1; o < 16; o <<= 1) {
                s += __shfl_xor(s, o);
                t += __shfl_xor(t, o);
            }
            if (col == 0 && row < n) { a_src[row] = s; a_dst[row] = t; }
        }
    } else {
        // ---------------- cscatter path ----------------
        int* sc    = meta;                // [NBC_MAX+1]
        int* offs  = meta + NBC_MAX + 1;  // [NBC_MAX]
        int* gbase = meta + 2 * NBC_MAX + 1;
        const int tid = threadIdx.x;
        for (int t = tid; t < nbc; t += 256) { sc[t] = 0; offs[t] = 0; }
        __syncthreads();
        const int base = ((int)blockIdx.x - gB) * 4096;
        int s_[16], d_[16];
#pragma unroll
        for (int k = 0; k < 4; ++k) {
            const int i0 = base + (k * 256 + tid) * 4;
            if (i0 + 4 <= e) {
                int4 s4 = *(const int4*)(srcv + i0);
                int4 d4 = *(const int4*)(dstv + i0);
                s_[k * 4 + 0] = s4.x; d_[k * 4 + 0] = d4.x;
                s_[k * 4 + 1] = s4.y; d_[k * 4 + 1] = d4.y;
                s_[k * 4 + 2] = s4.z; d_[k * 4 + 2] = d4.z;
                s_[k * 4 + 3] = s4.w; d_[k * 4 + 3] = d4.w;
            } else {
#pragma unroll
                for (int j = 0; j < 4; ++j) {
                    int i = i0 + j;
                    if (i < e) { s_[k * 4 + j] = srcv[i]; d_[k * 4 + j] = dstv[i]; }
                    else d_[k * 4 + j] = -1;
                }
            }
        }
#pragma unroll
        for (int k = 0; k < 16; ++k)
            if (d_[k] >= 0) atomicAdd(&sc[d_[k] >> 8], 1);
        lds_excl_scan(sc, nbc);
        for (int t = tid; t < nbc; t += 256) {
            int c = sc[t + 1] - sc[t];
            if (c) gbase[t] = t * SCAP + atomicAdd(&gcursor[t], c);
        }
        __syncthreads();
#pragma unroll
        for (int k = 0; k < 16; ++k) {
            if (d_[k] >= 0) {
                int bb = d_[k] >> 8;
                int r = atomicAdd(&offs[bb], 1);
                staged[sc[bb] + r] = make_int2(s_[k], d_[k]);
            }
        }
        __syncthreads();
        const int tot = sc[nbc];
        for (int p = tid; p < tot; p += 256) {
            int2 pr = staged[p];
            int bb = pr.y >> 8;
            int gi = gbase[bb] + (p - sc[bb]);
            if (gi < (bb + 1) * SCAP) {  // overflow clamp (never hot)
                words[gi] = ((pr.y & 255) << 17) | pr.x;  // dst_low:8|src:17
            }
        }
    }
}

// ------------------------------------------------- fine sort + edge exp
__global__ __launch_bounds__(256) void k_fsort(
    const int* __restrict__ words, const int* __restrict__ gcursor,
    const float* __restrict__ a_src, const float* __restrict__ a_dst,
    int2* __restrict__ ewp, int* __restrict__ rowptrB, int n) {
    __shared__ int rp[257];
    __shared__ int offs[256];
    __shared__ int sorted_[SCAP];   // 24 KB
    __shared__ float adst_l[256];
    const int b = blockIdx.x;
    const int d0 = b << 8;
    const int ndl = min(256, n - d0);
    const int base = b * SCAP;
    const int cnt = min(gcursor[b], SCAP);
    const int tid = threadIdx.x;
    rp[tid] = 0;
    offs[tid] = 0;
    if (tid == 0) rp[256] = 0;
    if (tid < ndl) adst_l[tid] = a_dst[d0 + tid];
    __syncthreads();
    for (int p = tid; p < cnt; p += 256)
        atomicAdd(&rp[(words[base + p] >> 17) & 255], 1);
    lds_excl_scan(rp, 256);
    for (int p = tid; p < cnt; p += 256) {
        int w = words[base + p];
        int dl = (w >> 17) & 255;
        int r = atomicAdd(&offs[dl], 1);
        sorted_[rp[dl] + r] = w;
    }
    __syncthreads();
    for (int p = tid; p < cnt; p += 256) {
        int w = sorted_[p];
        float al = __expf(leaky(a_src[w & 0x1FFFF] + adst_l[(w >> 17) & 255]));
        ewp[base + p] = make_int2(w, __float_as_int(al));
    }
    for (int t = tid; t <= 256; t += 256)
        rowptrB[b * 257 + t] = base + rp[t];
}

// ------------------------------------------------- weighted gather-aggregate
// 4 dsts per wave (16 lanes/dst); 32-edge chunks (2 guarded ewp loads/lane).
__global__ __launch_bounds__(256) void k_aggr(
    const unsigned short* __restrict__ h2, const float* __restrict__ a_src,
    const float* __restrict__ a_dst, const int* __restrict__ rowptrB,
    const int2* __restrict__ ewp, float* __restrict__ out, int n) {
    const int lane = threadIdx.x & 63;
    const int wave = threadIdx.x >> 6;
    const int d = blockIdx.x * 16 + wave * 4 + (lane >> 4);
    if (d >= n) return;
    const int b = d >> 8;
    const int dl = d & 255;
    const int s0 = rowptrB[b * 257 + dl];
    const int deg = rowptrB[b * 257 + dl + 1] - s0;
    const float wself = __expf(leaky(a_src[d] + a_dst[d]));

    const int r = (lane >> 3) & 1;    // row pair 0/1
    const int f0 = (lane & 7) << 3;   // feature octet
    const int gb = lane & 48;         // group base lane
    const int lane15 = lane & 15;
    float acc[8] = {0.f, 0.f, 0.f, 0.f, 0.f, 0.f, 0.f, 0.f};
    float wsum_l = 0.f;
    if (r == 0) {  // self loop
        int4 u = *(const int4*)(h2 + (size_t)d * 64 + f0);
        bf8_fma(acc, u, wself);
    }
    for (int cb = 0; cb < deg; cb += 32) {
        const int jA = cb + lane15;
        const int jB = jA + 16;
        int2 pA = make_int2(0, 0), pB = make_int2(0, 0);
        if (jA < deg) pA = ewp[s0 + jA];
        if (jB < deg) pB = ewp[s0 + jB];
        const int srcA = pA.x & 0x1FFFF;
        const float wA = __int_as_float(pA.y);
        const int srcB = pB.x & 0x1FFFF;
        const float wB = __int_as_float(pB.y);
        wsum_l += wA + wB;
        const int cnt = min(32, deg - cb);
#pragma unroll
        for (int c0 = 0; c0 < 16; c0 += 2) {
            const int sl = gb | (c0 + r);
            int sjA = __shfl(srcA, sl);
            float wjA = __shfl(wA, sl);
            int sjB = __shfl(srcB, sl);
            float wjB = __shfl(wB, sl);
            if (c0 + r < cnt) {
                int4 u = *(const int4*)(h2 + (size_t)sjA * 64 + f0);
                bf8_fma(acc, u, wjA);
            }
            if (16 + c0 + r < cnt) {
                int4 u = *(const int4*)(h2 + (size_t)sjB * 64 + f0);
                bf8_fma(acc, u, wjB);
            }
        }
    }
#pragma unroll
    for (int o = 8; o >= 1; o >>= 1) wsum_l += __shfl_xor(wsum_l, o);
    const float inv = 1.0f / (wsum_l + wself + 1e-16f);
#pragma unroll
    for (int i = 0; i < 8; ++i) acc[i] += __shfl_xor(acc[i], 8);
    if (r == 0) {
        float* op = out + (size_t)d * 64 + f0;
        *(float4*)op = make_float4(acc[0] * inv, acc[1] * inv,
                                   acc[2] * inv, acc[3] * inv);
        *(float4*)(op + 4) = make_float4(acc[4] * inv, acc[5] * inv,
                                         acc[6] * inv, acc[7] * inv);
    }
}

extern "C" void kernel_launch(void* const* d_in, const int* in_sizes, int n_in,
                              void* d_out, int out_size, void* d_ws, size_t ws_size,
                              hipStream_t stream) {
    const float* x = (const float*)d_in[0];
    const float* W = (const float*)d_in[1];
    const float* att_s = (const float*)d_in[2];
    const float* att_d = (const float*)d_in[3];
    const int* ei = (const int*)d_in[4];
    const int n = in_sizes[0] / 128;
    const int e = in_sizes[4] / 2;
    const int* srcv = ei;
    const int* dstv = ei + e;
    float* out = (float*)d_out;

    char* ws = (char*)d_ws;
    size_t off = 0;
    auto carve = [&](size_t bytes) -> void* {
        void* p = ws + off;
        off = (off + bytes + 63) & ~(size_t)63;
        return p;
    };
    const int nbc = (n + 255) >> 8;  // coarse buckets (<= NBC_MAX)
    unsigned short* h2 = (unsigned short*)carve((size_t)n * 64 * 2);
    float* a_src  = (float*)carve((size_t)n * 4);
    float* a_dst  = (float*)carve((size_t)n * 4);
    int* gcursor  = (int*)carve((size_t)NBC_MAX * 4);
    int* rowptrB  = (int*)carve((size_t)nbc * 257 * 4);
    int* words    = (int*)carve((size_t)nbc * SCAP * 4);
    int2* ewp     = (int2*)carve((size_t)nbc * SCAP * 8);
    (void)ws_size; (void)n_in; (void)out_size;

    const int neb = (e + 4095) / 4096;
    const int gB = (n + 63) / 64;

    hipMemsetAsync(gcursor, 0, (size_t)NBC_MAX * 4, stream);
    k_fused<<<gB + neb, 256, 0, stream>>>(x, W, att_s, att_d, h2, a_src, a_dst,
                                          srcv, dstv, gcursor, words, n, e, nbc, gB);
    k_fsort<<<nbc, 256, 0, stream>>>(words, gcursor, a_src, a_dst, ewp, rowptrB, n);
    k_aggr<<<(n + 15) / 16, 256, 0, stream>>>(h2, a_src, a_dst, rowptrB, ewp, out, n);
}

// Round 16
// 87.237 us; speedup vs baseline: 1.5656x; 1.0472x over previous
//
#include <hip/hip_runtime.h>

// GATConv fused pipeline, MI355X.
// R16: ewp intermediate slimmed 8B->4B/edge. k_fsort = pure counting sort
//   (no a_src gathers / exp / a_dst dependency; writes sorted words2).
//   k_aggr computes alpha inline per lane (parallel a_src gather + __expf —
//   the R8 serialization doesn't exist in lane-owns-edge form). Saves ~19MB
//   HBM round-trip + removes fsort's random-gather latency.
// k_fused (gemm|cscatter block-split) and aggr structure unchanged from R15.
// word = dst_low:8 | src:17 (n<=131072). rowptrB[b*257+dl] = abs seg starts.

#define NEG_SLOPE 0.2f
#define NBC_MAX 512
#define SCAP 6144

typedef __attribute__((ext_vector_type(8))) short bf16x8;
typedef __attribute__((ext_vector_type(4))) float f32x4;

__device__ __forceinline__ float leaky(float v) {
    return v > 0.f ? v : NEG_SLOPE * v;
}
__device__ __forceinline__ unsigned short f2bf(float f) {
    unsigned b = __float_as_uint(f);
    return (unsigned short)((b + 0x7FFFu + ((b >> 16) & 1u)) >> 16);
}
__device__ __forceinline__ float bf2f(unsigned short u) {
    return __uint_as_float(((unsigned)u) << 16);
}
// fma 8 bf16 features (packed in int4) into acc[8] with weight w
__device__ __forceinline__ void bf8_fma(float* acc, int4 u, float w) {
    acc[0] = fmaf(__uint_as_float((unsigned)u.x << 16), w, acc[0]);
    acc[1] = fmaf(__uint_as_float((unsigned)u.x & 0xFFFF0000u), w, acc[1]);
    acc[2] = fmaf(__uint_as_float((unsigned)u.y << 16), w, acc[2]);
    acc[3] = fmaf(__uint_as_float((unsigned)u.y & 0xFFFF0000u), w, acc[3]);
    acc[4] = fmaf(__uint_as_float((unsigned)u.z << 16), w, acc[4]);
    acc[5] = fmaf(__uint_as_float((unsigned)u.z & 0xFFFF0000u), w, acc[5]);
    acc[6] = fmaf(__uint_as_float((unsigned)u.w << 16), w, acc[6]);
    acc[7] = fmaf(__uint_as_float((unsigned)u.w & 0xFFFF0000u), w, acc[7]);
}

// exclusive scan of sd[0..len) in place; sd must have len+1 slots.
__device__ __forceinline__ void lds_excl_scan(int* sd, int len) {
    __syncthreads();
    if (threadIdx.x < 64) {
        int lane = threadIdx.x;
        int carry = 0;
        for (int c0 = 0; c0 < len; c0 += 64) {
            int idx = c0 + lane;
            int v = (idx < len) ? sd[idx] : 0;
            int s = v;
            for (int off = 1; off < 64; off <<= 1) {
                int t = __shfl_up(s, off);
                if (lane >= off) s += t;
            }
            if (idx < len) sd[idx] = carry + s - v;
            carry += __shfl(s, 63);
        }
        if (lane == 0) sd[len] = carry;
    }
    __syncthreads();
}

// ------------------------------------------------- fused gemm | cscatter
__global__ __launch_bounds__(256) void k_fused(
    const float* __restrict__ x, const float* __restrict__ Wg,
    const float* __restrict__ att_s, const float* __restrict__ att_d,
    unsigned short* __restrict__ h2, float* __restrict__ a_src,
    float* __restrict__ a_dst,
    const int* __restrict__ srcv, const int* __restrict__ dstv,
    int* __restrict__ gcursor, int* __restrict__ words,
    int n, int e, int nbc, int gB) {
    __shared__ int2 staged[4096];          // 32 KB (gemm: aliased as Wh)
    __shared__ int meta[NBC_MAX * 3 + 1];  // sc | offs | gbase

    if ((int)blockIdx.x < gB) {
        // ---------------- gemm path ----------------
        unsigned short* Wh = (unsigned short*)staged;  // [col][136]
        {
            const float4* wg4 = (const float4*)Wg;  // [k=128][col=64]
#pragma unroll
            for (int i = 0; i < 8; ++i) {
                int f = threadIdx.x + i * 256;
                float4 w = wg4[f];
                int k = f >> 4;
                int c0 = (f & 15) << 2;
                Wh[(c0 + 0) * 136 + k] = f2bf(w.x);
                Wh[(c0 + 1) * 136 + k] = f2bf(w.y);
                Wh[(c0 + 2) * 136 + k] = f2bf(w.z);
                Wh[(c0 + 3) * 136 + k] = f2bf(w.w);
            }
        }
        __syncthreads();

        const int lane = threadIdx.x & 63;
        const int wave = threadIdx.x >> 6;
        const int rb = blockIdx.x * 64 + wave * 16;
        const int arow = rb + (lane & 15);
        const int kb = (lane >> 4) << 3;
        const int col = lane & 15;

        f32x4 acc[4];
#pragma unroll
        for (int ct = 0; ct < 4; ++ct) acc[ct] = (f32x4){0.f, 0.f, 0.f, 0.f};

#pragma unroll
        for (int ks = 0; ks < 4; ++ks) {
            const int k0 = ks * 32 + kb;
            float av[8];
            if (arow < n) {
                float4 a0 = *(const float4*)(x + (size_t)arow * 128 + k0);
                float4 a1 = *(const float4*)(x + (size_t)arow * 128 + k0 + 4);
                av[0] = a0.x; av[1] = a0.y; av[2] = a0.z; av[3] = a0.w;
                av[4] = a1.x; av[5] = a1.y; av[6] = a1.z; av[7] = a1.w;
            } else {
#pragma unroll
                for (int j = 0; j < 8; ++j) av[j] = 0.f;
            }
            bf16x8 ah;
#pragma unroll
            for (int j = 0; j < 8; ++j) ah[j] = (short)f2bf(av[j]);
#pragma unroll
            for (int ct = 0; ct < 4; ++ct) {
                const bf16x8 bh = *(const bf16x8*)(&Wh[(ct * 16 + col) * 136 + k0]);
                acc[ct] = __builtin_amdgcn_mfma_f32_16x16x32_bf16(ah, bh, acc[ct], 0, 0, 0);
            }
        }

        float as_f[4], ad_f[4];
#pragma unroll
        for (int ct = 0; ct < 4; ++ct) {
            as_f[ct] = att_s[ct * 16 + col];
            ad_f[ct] = att_d[ct * 16 + col];
        }
#pragma unroll
        for (int reg = 0; reg < 4; ++reg) {
            const int row = rb + ((lane >> 4) << 2) + reg;
            float s = 0.f, t = 0.f;
#pragma unroll
            for (int ct = 0; ct < 4; ++ct) {
                float v = acc[ct][reg];
                s = fmaf(v, as_f[ct], s);
                t = fmaf(v, ad_f[ct], t);
                if (row < n) h2[(size_t)row * 64 + ct * 16 + col] = f2bf(v);
            }
#pragma unroll
            for (int o = 1; o < 16; o <<= 1) {
                s += __shfl_xor(s, o);
                t += __shfl_xor(t, o);
            }
            if (col == 0 && row < n) { a_src[row] = s; a_dst[row] = t; }
        }
    } else {
        // ---------------- cscatter path ----------------
        int* sc    = meta;                // [NBC_MAX+1]
        int* offs  = meta + NBC_MAX + 1;  // [NBC_MAX]
        int* gbase = meta + 2 * NBC_MAX + 1;
        const int tid = threadIdx.x;
        for (int t = tid; t < nbc; t += 256) { sc[t] = 0; offs[t] = 0; }
        __syncthreads();
        const int base = ((int)blockIdx.x - gB) * 4096;
        int s_[16], d_[16];
#pragma unroll
        for (int k = 0; k < 4; ++k) {
            const int i0 = base + (k * 256 + tid) * 4;
            if (i0 + 4 <= e) {
                int4 s4 = *(const int4*)(srcv + i0);
                int4 d4 = *(const int4*)(dstv + i0);
                s_[k * 4 + 0] = s4.x; d_[k * 4 + 0] = d4.x;
                s_[k * 4 + 1] = s4.y; d_[k * 4 + 1] = d4.y;
                s_[k * 4 + 2] = s4.z; d_[k * 4 + 2] = d4.z;
                s_[k * 4 + 3] = s4.w; d_[k * 4 + 3] = d4.w;
            } else {
#pragma unroll
                for (int j = 0; j < 4; ++j) {
                    int i = i0 + j;
                    if (i < e) { s_[k * 4 + j] = srcv[i]; d_[k * 4 + j] = dstv[i]; }
                    else d_[k * 4 + j] = -1;
                }
            }
        }
#pragma unroll
        for (int k = 0; k < 16; ++k)
            if (d_[k] >= 0) atomicAdd(&sc[d_[k] >> 8], 1);
        lds_excl_scan(sc, nbc);
        for (int t = tid; t < nbc; t += 256) {
            int c = sc[t + 1] - sc[t];
            if (c) gbase[t] = t * SCAP + atomicAdd(&gcursor[t], c);
        }
        __syncthreads();
#pragma unroll
        for (int k = 0; k < 16; ++k) {
            if (d_[k] >= 0) {
                int bb = d_[k] >> 8;
                int r = atomicAdd(&offs[bb], 1);
                staged[sc[bb] + r] = make_int2(s_[k], d_[k]);
            }
        }
        __syncthreads();
        const int tot = sc[nbc];
        for (int p = tid; p < tot; p += 256) {
            int2 pr = staged[p];
            int bb = pr.y >> 8;
            int gi = gbase[bb] + (p - sc[bb]);
            if (gi < (bb + 1) * SCAP) {  // overflow clamp (never hot)
                words[gi] = ((pr.y & 255) << 17) | pr.x;  // dst_low:8|src:17
            }
        }
    }
}

// ------------------------------------------------- fine sort (pure)
// counting-sort bucket by dst_low; writes sorted words2 (4B/edge) + rowptrB.
// No gathers, no exp — no dependency on gemm outputs.
__global__ __launch_bounds__(256) void k_fsort(
    const int* __restrict__ words, const int* __restrict__ gcursor,
    int* __restrict__ words2, int* __restrict__ rowptrB, int n) {
    __shared__ int rp[257];
    __shared__ int offs[256];
    __shared__ int sorted_[SCAP];   // 24 KB
    const int b = blockIdx.x;
    const int base = b * SCAP;
    const int cnt = min(gcursor[b], SCAP);
    const int tid = threadIdx.x;
    rp[tid] = 0;
    offs[tid] = 0;
    if (tid == 0) rp[256] = 0;
    __syncthreads();
    for (int p = tid; p < cnt; p += 256)
        atomicAdd(&rp[(words[base + p] >> 17) & 255], 1);
    lds_excl_scan(rp, 256);
    for (int p = tid; p < cnt; p += 256) {
        int w = words[base + p];
        int dl = (w >> 17) & 255;
        int r = atomicAdd(&offs[dl], 1);
        sorted_[rp[dl] + r] = w;
    }
    __syncthreads();
    for (int p = tid; p < cnt; p += 256) words2[base + p] = sorted_[p];
    for (int t = tid; t <= 256; t += 256)
        rowptrB[b * 257 + t] = base + rp[t];
}

// ------------------------------------------------- weighted gather-aggregate
// 4 dsts/wave (16 lanes/dst); 32-edge chunks; alpha computed inline per lane
// (parallel a_src gather + __expf — bit-identical math to fsort-precompute).
__global__ __launch_bounds__(256) void k_aggr(
    const unsigned short* __restrict__ h2, const float* __restrict__ a_src,
    const float* __restrict__ a_dst, const int* __restrict__ rowptrB,
    const int* __restrict__ words2, float* __restrict__ out, int n) {
    const int lane = threadIdx.x & 63;
    const int wave = threadIdx.x >> 6;
    const int d = blockIdx.x * 16 + wave * 4 + (lane >> 4);
    if (d >= n) return;
    const int b = d >> 8;
    const int dl = d & 255;
    const int s0 = rowptrB[b * 257 + dl];
    const int deg = rowptrB[b * 257 + dl + 1] - s0;
    const float adstd = a_dst[d];
    const float wself = __expf(leaky(a_src[d] + adstd));

    const int r = (lane >> 3) & 1;    // row pair 0/1
    const int f0 = (lane & 7) << 3;   // feature octet
    const int gb = lane & 48;         // group base lane
    const int lane15 = lane & 15;
    float acc[8] = {0.f, 0.f, 0.f, 0.f, 0.f, 0.f, 0.f, 0.f};
    float wsum_l = 0.f;
    if (r == 0) {  // self loop
        int4 u = *(const int4*)(h2 + (size_t)d * 64 + f0);
        bf8_fma(acc, u, wself);
    }
    for (int cb = 0; cb < deg; cb += 32) {
        const int jA = cb + lane15;
        const int jB = jA + 16;
        int srcA = 0, srcB = 0;
        float wA = 0.f, wB = 0.f;
        if (jA < deg) srcA = words2[s0 + jA] & 0x1FFFF;
        if (jB < deg) srcB = words2[s0 + jB] & 0x1FFFF;
        if (jA < deg) wA = __expf(leaky(a_src[srcA] + adstd));
        if (jB < deg) wB = __expf(leaky(a_src[srcB] + adstd));
        wsum_l += wA + wB;
        const int cnt = min(32, deg - cb);
#pragma unroll
        for (int c0 = 0; c0 < 16; c0 += 2) {
            const int sl = gb | (c0 + r);
            int sjA = __shfl(srcA, sl);
            float wjA = __shfl(wA, sl);
            int sjB = __shfl(srcB, sl);
            float wjB = __shfl(wB, sl);
            if (c0 + r < cnt) {
                int4 u = *(const int4*)(h2 + (size_t)sjA * 64 + f0);
                bf8_fma(acc, u, wjA);
            }
            if (16 + c0 + r < cnt) {
                int4 u = *(const int4*)(h2 + (size_t)sjB * 64 + f0);
                bf8_fma(acc, u, wjB);
            }
        }
    }
#pragma unroll
    for (int o = 8; o >= 1; o >>= 1) wsum_l += __shfl_xor(wsum_l, o);
    const float inv = 1.0f / (wsum_l + wself + 1e-16f);
#pragma unroll
    for (int i = 0; i < 8; ++i) acc[i] += __shfl_xor(acc[i], 8);
    if (r == 0) {
        float* op = out + (size_t)d * 64 + f0;
        *(float4*)op = make_float4(acc[0] * inv, acc[1] * inv,
                                   acc[2] * inv, acc[3] * inv);
        *(float4*)(op + 4) = make_float4(acc[4] * inv, acc[5] * inv,
                                         acc[6] * inv, acc[7] * inv);
    }
}

extern "C" void kernel_launch(void* const* d_in, const int* in_sizes, int n_in,
                              void* d_out, int out_size, void* d_ws, size_t ws_size,
                              hipStream_t stream) {
    const float* x = (const float*)d_in[0];
    const float* W = (const float*)d_in[1];
    const float* att_s = (const float*)d_in[2];
    const float* att_d = (const float*)d_in[3];
    const int* ei = (const int*)d_in[4];
    const int n = in_sizes[0] / 128;
    const int e = in_sizes[4] / 2;
    const int* srcv = ei;
    const int* dstv = ei + e;
    float* out = (float*)d_out;

    char* ws = (char*)d_ws;
    size_t off = 0;
    auto carve = [&](size_t bytes) -> void* {
        void* p = ws + off;
        off = (off + bytes + 63) & ~(size_t)63;
        return p;
    };
    const int nbc = (n + 255) >> 8;  // coarse buckets (<= NBC_MAX)
    unsigned short* h2 = (unsigned short*)carve((size_t)n * 64 * 2);
    float* a_src  = (float*)carve((size_t)n * 4);
    float* a_dst  = (float*)carve((size_t)n * 4);
    int* gcursor  = (int*)carve((size_t)NBC_MAX * 4);
    int* rowptrB  = (int*)carve((size_t)nbc * 257 * 4);
    int* words    = (int*)carve((size_t)nbc * SCAP * 4);
    int* words2   = (int*)carve((size_t)nbc * SCAP * 4);
    (void)ws_size; (void)n_in; (void)out_size;

    const int neb = (e + 4095) / 4096;
    const int gB = (n + 63) / 64;

    hipMemsetAsync(gcursor, 0, (size_t)NBC_MAX * 4, stream);
    k_fused<<<gB + neb, 256, 0, stream>>>(x, W, att_s, att_d, h2, a_src, a_dst,
                                          srcv, dstv, gcursor, words, n, e, nbc, gB);
    k_fsort<<<nbc, 256, 0, stream>>>(words, gcursor, words2, rowptrB, n);
    k_aggr<<<(n + 15) / 16, 256, 0, stream>>>(h2, a_src, a_dst, rowptrB, words2, out, n);
}

// Round 17
// 86.563 us; speedup vs baseline: 1.5778x; 1.0078x over previous
//
#include <hip/hip_runtime.h>

// GATConv fused pipeline, MI355X.
// R17: (1) fused kernel path order SWAPPED: scatter = blocks [0,neb), gemm
//   after — blocks dispatch in blockIdx order, so R15's layout filled all
//   resident slots with gemm before any scatter ran (fusion was quasi-serial).
//   (2) scatter LDS slimmed 38.9->30KB (word int + bucket ushort staging,
//   single carved buffer) -> 5 blocks/CU both paths. (3) fsort single global
//   read (LDS staging) + int4 words2 writes. aggr unchanged (at L2-miss floor).
// word = dst_low:8 | src:17 (n<=131072). rowptrB[b*257+dl] = abs seg starts.

#define NEG_SLOPE 0.2f
#define NBC_MAX 512
#define SCAP 6144

typedef __attribute__((ext_vector_type(8))) short bf16x8;
typedef __attribute__((ext_vector_type(4))) float f32x4;

__device__ __forceinline__ float leaky(float v) {
    return v > 0.f ? v : NEG_SLOPE * v;
}
__device__ __forceinline__ unsigned short f2bf(float f) {
    unsigned b = __float_as_uint(f);
    return (unsigned short)((b + 0x7FFFu + ((b >> 16) & 1u)) >> 16);
}
__device__ __forceinline__ float bf2f(unsigned short u) {
    return __uint_as_float(((unsigned)u) << 16);
}
// fma 8 bf16 features (packed in int4) into acc[8] with weight w
__device__ __forceinline__ void bf8_fma(float* acc, int4 u, float w) {
    acc[0] = fmaf(__uint_as_float((unsigned)u.x << 16), w, acc[0]);
    acc[1] = fmaf(__uint_as_float((unsigned)u.x & 0xFFFF0000u), w, acc[1]);
    acc[2] = fmaf(__uint_as_float((unsigned)u.y << 16), w, acc[2]);
    acc[3] = fmaf(__uint_as_float((unsigned)u.y & 0xFFFF0000u), w, acc[3]);
    acc[4] = fmaf(__uint_as_float((unsigned)u.z << 16), w, acc[4]);
    acc[5] = fmaf(__uint_as_float((unsigned)u.z & 0xFFFF0000u), w, acc[5]);
    acc[6] = fmaf(__uint_as_float((unsigned)u.w << 16), w, acc[6]);
    acc[7] = fmaf(__uint_as_float((unsigned)u.w & 0xFFFF0000u), w, acc[7]);
}

// exclusive scan of sd[0..len) in place; sd must have len+1 slots.
__device__ __forceinline__ void lds_excl_scan(int* sd, int len) {
    __syncthreads();
    if (threadIdx.x < 64) {
        int lane = threadIdx.x;
        int carry = 0;
        for (int c0 = 0; c0 < len; c0 += 64) {
            int idx = c0 + lane;
            int v = (idx < len) ? sd[idx] : 0;
            int s = v;
            for (int off = 1; off < 64; off <<= 1) {
                int t = __shfl_up(s, off);
                if (lane >= off) s += t;
            }
            if (idx < len) sd[idx] = carry + s - v;
            carry += __shfl(s, 63);
        }
        if (lane == 0) sd[len] = carry;
    }
    __syncthreads();
}

// ------------------------------------------------- fused cscatter | gemm
// blocks [0, neb): coarse scatter. blocks [neb, neb+gB): gemm.
// LDS carve: scatter: wordA int[4096] | buckA ushort[4096] | meta 1537 ints.
//            gemm:    Wh ushort[64*136] (17408 B, fits in first 24576).
__global__ __launch_bounds__(256) void k_fused(
    const float* __restrict__ x, const float* __restrict__ Wg,
    const float* __restrict__ att_s, const float* __restrict__ att_d,
    unsigned short* __restrict__ h2, float* __restrict__ a_src,
    float* __restrict__ a_dst,
    const int* __restrict__ srcv, const int* __restrict__ dstv,
    int* __restrict__ gcursor, int* __restrict__ words,
    int n, int e, int nbc, int neb) {
    __shared__ char sbuf[16384 + 8192 + (NBC_MAX * 3 + 1) * 4];  // 30.7 KB

    if ((int)blockIdx.x >= neb) {
        // ---------------- gemm path ----------------
        unsigned short* Wh = (unsigned short*)sbuf;  // [col][136]
        {
            const float4* wg4 = (const float4*)Wg;  // [k=128][col=64]
#pragma unroll
            for (int i = 0; i < 8; ++i) {
                int f = threadIdx.x + i * 256;
                float4 w = wg4[f];
                int k = f >> 4;
                int c0 = (f & 15) << 2;
                Wh[(c0 + 0) * 136 + k] = f2bf(w.x);
                Wh[(c0 + 1) * 136 + k] = f2bf(w.y);
                Wh[(c0 + 2) * 136 + k] = f2bf(w.z);
                Wh[(c0 + 3) * 136 + k] = f2bf(w.w);
            }
        }
        __syncthreads();

        const int lane = threadIdx.x & 63;
        const int wave = threadIdx.x >> 6;
        const int rb = ((int)blockIdx.x - neb) * 64 + wave * 16;
        const int arow = rb + (lane & 15);
        const int kb = (lane >> 4) << 3;
        const int col = lane & 15;

        f32x4 acc[4];
#pragma unroll
        for (int ct = 0; ct < 4; ++ct) acc[ct] = (f32x4){0.f, 0.f, 0.f, 0.f};

#pragma unroll
        for (int ks = 0; ks < 4; ++ks) {
            const int k0 = ks * 32 + kb;
            float av[8];
            if (arow < n) {
                float4 a0 = *(const float4*)(x + (size_t)arow * 128 + k0);
                float4 a1 = *(const float4*)(x + (size_t)arow * 128 + k0 + 4);
                av[0] = a0.x; av[1] = a0.y; av[2] = a0.z; av[3] = a0.w;
                av[4] = a1.x; av[5] = a1.y; av[6] = a1.z; av[7] = a1.w;
            } else {
#pragma unroll
                for (int j = 0; j < 8; ++j) av[j] = 0.f;
            }
            bf16x8 ah;
#pragma unroll
            for (int j = 0; j < 8; ++j) ah[j] = (short)f2bf(av[j]);
#pragma unroll
            for (int ct = 0; ct < 4; ++ct) {
                const bf16x8 bh = *(const bf16x8*)(&Wh[(ct * 16 + col) * 136 + k0]);
                acc[ct] = __builtin_amdgcn_mfma_f32_16x16x32_bf16(ah, bh, acc[ct], 0, 0, 0);
            }
        }

        float as_f[4], ad_f[4];
#pragma unroll
        for (int ct = 0; ct < 4; ++ct) {
            as_f[ct] = att_s[ct * 16 + col];
            ad_f[ct] = att_d[ct * 16 + col];
        }
#pragma unroll
        for (int reg = 0; reg < 4; ++reg) {
            const int row = rb + ((lane >> 4) << 2) + reg;
            float s = 0.f, t = 0.f;
#pragma unroll
            for (int ct = 0; ct < 4; ++ct) {
                float v = acc[ct][reg];
                s = fmaf(v, as_f[ct], s);
                t = fmaf(v, ad_f[ct], t);
                if (row < n) h2[(size_t)row * 64 + ct * 16 + col] = f2bf(v);
            }
#pragma unroll
            for (int o = 1; o < 16; o <<= 1) {
                s += __shfl_xor(s, o);
                t += __shfl_xor(t, o);
            }
            if (col == 0 && row < n) { a_src[row] = s; a_dst[row] = t; }
        }
    } else {
        // ---------------- cscatter path ----------------
        int* wordA = (int*)sbuf;                            // [4096]
        unsigned short* buckA = (unsigned short*)(sbuf + 16384);  // [4096]
        int* meta  = (int*)(sbuf + 24576);
        int* sc    = meta;                 // [NBC_MAX+1]
        int* offs  = meta + NBC_MAX + 1;   // [NBC_MAX]
        int* gbase = meta + 2 * NBC_MAX + 1;
        const int tid = threadIdx.x;
        for (int t = tid; t < nbc; t += 256) { sc[t] = 0; offs[t] = 0; }
        __syncthreads();
        const int base = (int)blockIdx.x * 4096;
        int s_[16], d_[16];
#pragma unroll
        for (int k = 0; k < 4; ++k) {
            const int i0 = base + (k * 256 + tid) * 4;
            if (i0 + 4 <= e) {
                int4 s4 = *(const int4*)(srcv + i0);
                int4 d4 = *(const int4*)(dstv + i0);
                s_[k * 4 + 0] = s4.x; d_[k * 4 + 0] = d4.x;
                s_[k * 4 + 1] = s4.y; d_[k * 4 + 1] = d4.y;
                s_[k * 4 + 2] = s4.z; d_[k * 4 + 2] = d4.z;
                s_[k * 4 + 3] = s4.w; d_[k * 4 + 3] = d4.w;
            } else {
#pragma unroll
                for (int j = 0; j < 4; ++j) {
                    int i = i0 + j;
                    if (i < e) { s_[k * 4 + j] = srcv[i]; d_[k * 4 + j] = dstv[i]; }
                    else d_[k * 4 + j] = -1;
                }
            }
        }
#pragma unroll
        for (int k = 0; k < 16; ++k)
            if (d_[k] >= 0) atomicAdd(&sc[d_[k] >> 8], 1);
        lds_excl_scan(sc, nbc);
        for (int t = tid; t < nbc; t += 256) {
            int c = sc[t + 1] - sc[t];
            if (c) gbase[t] = t * SCAP + atomicAdd(&gcursor[t], c);
        }
        __syncthreads();
#pragma unroll
        for (int k = 0; k < 16; ++k) {
            if (d_[k] >= 0) {
                int bb = d_[k] >> 8;
                int r = atomicAdd(&offs[bb], 1);
                int idx = sc[bb] + r;
                wordA[idx] = ((d_[k] & 255) << 17) | s_[k];
                buckA[idx] = (unsigned short)bb;
            }
        }
        __syncthreads();
        const int tot = sc[nbc];
        for (int p = tid; p < tot; p += 256) {
            int bb = buckA[p];
            int gi = gbase[bb] + (p - sc[bb]);
            if (gi < (bb + 1) * SCAP) {  // overflow clamp (never hot)
                words[gi] = wordA[p];
            }
        }
    }
}

// ------------------------------------------------- fine sort (pure, 1-read)
// counting-sort bucket by dst_low; single global read (LDS staged);
// int4-vectorized words2 writes + rowptrB.
__global__ __launch_bounds__(256) void k_fsort(
    const int* __restrict__ words, const int* __restrict__ gcursor,
    int* __restrict__ words2, int* __restrict__ rowptrB, int n) {
    __shared__ int rp[257];
    __shared__ int offs[256];
    __shared__ int staged[SCAP];    // 24 KB
    __shared__ int sorted_[SCAP];   // 24 KB
    const int b = blockIdx.x;
    const int base = b * SCAP;
    const int cnt = min(gcursor[b], SCAP);
    const int tid = threadIdx.x;
    rp[tid] = 0;
    offs[tid] = 0;
    if (tid == 0) rp[256] = 0;
    __syncthreads();
    for (int p = tid; p < cnt; p += 256) {
        int w = words[base + p];
        staged[p] = w;
        atomicAdd(&rp[(w >> 17) & 255], 1);
    }
    lds_excl_scan(rp, 256);
    for (int p = tid; p < cnt; p += 256) {
        int w = staged[p];
        int dl = (w >> 17) & 255;
        int r = atomicAdd(&offs[dl], 1);
        sorted_[rp[dl] + r] = w;
    }
    __syncthreads();
    const int cnt4 = cnt >> 2;
    for (int q = tid; q < cnt4; q += 256)
        ((int4*)(words2 + base))[q] = ((const int4*)sorted_)[q];
    for (int p = (cnt4 << 2) + tid; p < cnt; p += 256)
        words2[base + p] = sorted_[p];
    for (int t = tid; t <= 256; t += 256)
        rowptrB[b * 257 + t] = base + rp[t];
}

// ------------------------------------------------- weighted gather-aggregate
// 4 dsts/wave (16 lanes/dst); 32-edge chunks; alpha computed inline per lane.
__global__ __launch_bounds__(256) void k_aggr(
    const unsigned short* __restrict__ h2, const float* __restrict__ a_src,
    const float* __restrict__ a_dst, const int* __restrict__ rowptrB,
    const int* __restrict__ words2, float* __restrict__ out, int n) {
    const int lane = threadIdx.x & 63;
    const int wave = threadIdx.x >> 6;
    const int d = blockIdx.x * 16 + wave * 4 + (lane >> 4);
    if (d >= n) return;
    const int b = d >> 8;
    const int dl = d & 255;
    const int s0 = rowptrB[b * 257 + dl];
    const int deg = rowptrB[b * 257 + dl + 1] - s0;
    const float adstd = a_dst[d];
    const float wself = __expf(leaky(a_src[d] + adstd));

    const int r = (lane >> 3) & 1;    // row pair 0/1
    const int f0 = (lane & 7) << 3;   // feature octet
    const int gb = lane & 48;         // group base lane
    const int lane15 = lane & 15;
    float acc[8] = {0.f, 0.f, 0.f, 0.f, 0.f, 0.f, 0.f, 0.f};
    float wsum_l = 0.f;
    if (r == 0) {  // self loop
        int4 u = *(const int4*)(h2 + (size_t)d * 64 + f0);
        bf8_fma(acc, u, wself);
    }
    for (int cb = 0; cb < deg; cb += 32) {
        const int jA = cb + lane15;
        const int jB = jA + 16;
        int srcA = 0, srcB = 0;
        float wA = 0.f, wB = 0.f;
        if (jA < deg) srcA = words2[s0 + jA] & 0x1FFFF;
        if (jB < deg) srcB = words2[s0 + jB] & 0x1FFFF;
        if (jA < deg) wA = __expf(leaky(a_src[srcA] + adstd));
        if (jB < deg) wB = __expf(leaky(a_src[srcB] + adstd));
        wsum_l += wA + wB;
        const int cnt = min(32, deg - cb);
#pragma unroll
        for (int c0 = 0; c0 < 16; c0 += 2) {
            const int sl = gb | (c0 + r);
            int sjA = __shfl(srcA, sl);
            float wjA = __shfl(wA, sl);
            int sjB = __shfl(srcB, sl);
            float wjB = __shfl(wB, sl);
            if (c0 + r < cnt) {
                int4 u = *(const int4*)(h2 + (size_t)sjA * 64 + f0);
                bf8_fma(acc, u, wjA);
            }
            if (16 + c0 + r < cnt) {
                int4 u = *(const int4*)(h2 + (size_t)sjB * 64 + f0);
                bf8_fma(acc, u, wjB);
            }
        }
    }
#pragma unroll
    for (int o = 8; o >= 1; o >>= 1) wsum_l += __shfl_xor(wsum_l, o);
    const float inv = 1.0f / (wsum_l + wself + 1e-16f);
#pragma unroll
    for (int i = 0; i < 8; ++i) acc[i] += __shfl_xor(acc[i], 8);
    if (r == 0) {
        float* op = out + (size_t)d * 64 + f0;
        *(float4*)op = make_float4(acc[0] * inv, acc[1] * inv,
                                   acc[2] * inv, acc[3] * inv);
        *(float4*)(op + 4) = make_float4(acc[4] * inv, acc[5] * inv,
                                         acc[6] * inv, acc[7] * inv);
    }
}

extern "C" void kernel_launch(void* const* d_in, const int* in_sizes, int n_in,
                              void* d_out, int out_size, void* d_ws, size_t ws_size,
                              hipStream_t stream) {
    const float* x = (const float*)d_in[0];
    const float* W = (const float*)d_in[1];
    const float* att_s = (const float*)d_in[2];
    const float* att_d = (const float*)d_in[3];
    const int* ei = (const int*)d_in[4];
    const int n = in_sizes[0] / 128;
    const int e = in_sizes[4] / 2;
    const int* srcv = ei;
    const int* dstv = ei + e;
    float* out = (float*)d_out;

    char* ws = (char*)d_ws;
    size_t off = 0;
    auto carve = [&](size_t bytes) -> void* {
        void* p = ws + off;
        off = (off + bytes + 63) & ~(size_t)63;
        return p;
    };
    const int nbc = (n + 255) >> 8;  // coarse buckets (<= NBC_MAX)
    unsigned short* h2 = (unsigned short*)carve((size_t)n * 64 * 2);
    float* a_src  = (float*)carve((size_t)n * 4);
    float* a_dst  = (float*)carve((size_t)n * 4);
    int* gcursor  = (int*)carve((size_t)NBC_MAX * 4);
    int* rowptrB  = (int*)carve((size_t)nbc * 257 * 4);
    int* words    = (int*)carve((size_t)nbc * SCAP * 4);
    int* words2   = (int*)carve((size_t)nbc * SCAP * 4);
    (void)ws_size; (void)n_in; (void)out_size;

    const int neb = (e + 4095) / 4096;
    const int gB = (n + 63) / 64;

    hipMemsetAsync(gcursor, 0, (size_t)NBC_MAX * 4, stream);
    k_fused<<<neb + gB, 256, 0, stream>>>(x, W, att_s, att_d, h2, a_src, a_dst,
                                          srcv, dstv, gcursor, words, n, e, nbc, neb);
    k_fsort<<<nbc, 256, 0, stream>>>(words, gcursor, words2, rowptrB, n);
    k_aggr<<<(n + 15) / 16, 256, 0, stream>>>(h2, a_src, a_dst, rowptrB, words2, out, n);
}